// Round 5
// baseline (523.031 us; speedup 1.0000x reference)
//
#include <hip/hip_runtime.h>
#include <hip/hip_bf16.h>
#include <math.h>

#define D_DIM 768
#define B_DIM 64
#define L_DIM 512
#define M_DIM (B_DIM * L_DIM)   /* 32768 rows */
#define YD 3
#define ZD 5
#define LN_EPS 1e-5f
#define COS_EPS 1e-8f

typedef short short8v __attribute__((ext_vector_type(8)));
typedef float f32x4  __attribute__((ext_vector_type(4)));

// ---------------------------------------------------------------------------
// bf16 helpers (RNE), split x = hi + lo with hi,lo bf16; |err| <= 2^-17 |x|
// ---------------------------------------------------------------------------
__device__ __forceinline__ unsigned short f2bf(float f) {
    unsigned u = __builtin_bit_cast(unsigned, f);
    u = (u + 0x7fffu + ((u >> 16) & 1u)) >> 16;
    return (unsigned short)u;
}
__device__ __forceinline__ float bf2f(unsigned short h) {
    unsigned u = ((unsigned)h) << 16;
    return __builtin_bit_cast(float, u);
}
__device__ __forceinline__ void split2(float v, unsigned short& h, unsigned short& l) {
    h = f2bf(v);
    l = f2bf(v - bf2f(h));
}

// async global->LDS, 16B per lane, wave-uniform LDS base + lane*16
__device__ __forceinline__ void gld16(const void* g, void* l) {
    __builtin_amdgcn_global_load_lds(
        (const __attribute__((address_space(1))) void*)g,
        (__attribute__((address_space(3))) void*)l, 16, 0, 0);
}

// ---------------------------------------------------------------------------
// split emb -> hi/lo bf16 (vectorized, 4 elems/thread)
// ---------------------------------------------------------------------------
__global__ __launch_bounds__(256)
void split_kernel(const float* __restrict__ in, unsigned short* __restrict__ hi,
                  unsigned short* __restrict__ lo, int n4)
{
    const int i = blockIdx.x * 256 + threadIdx.x;
    if (i >= n4) return;
    const float4 v = reinterpret_cast<const float4*>(in)[i];
    ushort4 h, l;
    split2(v.x, h.x, l.x); split2(v.y, h.y, l.y);
    split2(v.z, h.z, l.z); split2(v.w, h.w, l.w);
    reinterpret_cast<ushort4*>(hi)[i] = h;
    reinterpret_cast<ushort4*>(lo)[i] = l;
}

// ---------------------------------------------------------------------------
// W[768][768] -> Wt_hi/Wt_lo[n][k] (transposed, split). 32x32 LDS tiles.
// ---------------------------------------------------------------------------
__global__ __launch_bounds__(256)
void tsplit_kernel(const float* __restrict__ W, unsigned short* __restrict__ thi,
                   unsigned short* __restrict__ tlo)
{
    __shared__ float t[32][33];
    const int tx = threadIdx.x & 31, ty = threadIdx.x >> 5;
    const int n0 = blockIdx.x * 32, k0 = blockIdx.y * 32;
    #pragma unroll
    for (int j = 0; j < 4; ++j)
        t[ty + 8 * j][tx] = W[(size_t)(k0 + ty + 8 * j) * D_DIM + n0 + tx];
    __syncthreads();
    #pragma unroll
    for (int j = 0; j < 4; ++j) {
        const float v = t[tx][ty + 8 * j];
        unsigned short h, l; split2(v, h, l);
        const size_t o = (size_t)(n0 + ty + 8 * j) * D_DIM + k0 + tx;
        thi[o] = h; tlo[o] = l;
    }
}

// ---------------------------------------------------------------------------
// MFMA GEMM: out[M,768] = epilogue( (Ahi+Alo) @ (Bhi+Blo)^T' + bias )
//   3-term split product: Ahi*Bhi + Ahi*Blo + Alo*Bhi  (fp32 acc, 16x16x32)
// MODE 0: h = relu(acc+bias) -> write split bf16 hi/lo
// MODE 1: write float acc + bias + resid
// 128x128 tile, BK=32, 256 thr (4 waves 2x2), wave tile 64x64 (4x4 frags).
// T1 XCD swizzle (1536 wgs %8==0). LDS slot XOR-swizzle on BOTH the global
// source and the ds_read (G21). T3-minimum 2-phase: double-buffered LDS,
// prefetch next K-tile BEFORE compute, ONE barrier per K-step — loads land
// during the 48-MFMA phase instead of stalling at the barrier drain.
// ---------------------------------------------------------------------------
template<int MODE>
__global__ __launch_bounds__(256, 2)
void gemm_mfma(const unsigned short* __restrict__ Ahi, const unsigned short* __restrict__ Alo,
               const unsigned short* __restrict__ Bhi, const unsigned short* __restrict__ Blo,
               const float* __restrict__ bias, const float* __restrict__ resid,
               unsigned short* __restrict__ out_hi, unsigned short* __restrict__ out_lo,
               float* __restrict__ out_f)
{
    // double-buffered: [0,512) = buffer 0, [512,1024) = buffer 1 (4 x 16KB)
    __shared__ short8v As_hi[1024], As_lo[1024], Bs_hi[1024], Bs_lo[1024];

    // ---- XCD-aware swizzle: lin -> lid, then (bx,by) ----
    const int lin = blockIdx.y * gridDim.x + blockIdx.x;     // hw linear id
    const int cpx = (gridDim.x * gridDim.y) >> 3;            // 192
    const int lid = (lin & 7) * cpx + (lin >> 3);
    const int bx  = lid % 6;
    const int by  = lid / 6;

    const int tid  = threadIdx.x;
    const int w    = tid >> 6;
    const int lane = tid & 63;
    const int m0   = by * 128;
    const int n0   = bx * 128;
    const int wm   = (w >> 1) * 64;     // wave tile origin in block
    const int wn   = (w & 1) * 64;

    // ---- staging source pointers (pre-swizzled global addresses, m173) ----
    const int rr = lane >> 2;          // row-within-1KB-chunk
    const int cc = lane & 3;           // 16B slot
    const int r0 = w * 32 + rr;        // chunk q=0 row (0..127)
    const int r1 = r0 + 16;            // chunk q=1 row
    const int sw0 = (cc ^ ((r0 >> 1) & 3)) * 16;   // swizzled byte-slot in row
    const int sw1 = (cc ^ ((r1 >> 1) & 3)) * 16;
    const size_t aoff0 = (size_t)(m0 + r0) * 1536 + sw0;  // 768*2B row stride
    const size_t aoff1 = (size_t)(m0 + r1) * 1536 + sw1;
    const size_t boff0 = (size_t)(n0 + r0) * 1536 + sw0;
    const size_t boff1 = (size_t)(n0 + r1) * 1536 + sw1;
    const char* pAhi = (const char*)Ahi; const char* pAlo = (const char*)Alo;
    const char* pBhi = (const char*)Bhi; const char* pBlo = (const char*)Blo;
    short8v* const dAh0 = As_hi + w * 128;      short8v* const dAh1 = dAh0 + 64;
    short8v* const dAl0 = As_lo + w * 128;      short8v* const dAl1 = dAl0 + 64;
    short8v* const dBh0 = Bs_hi + w * 128;      short8v* const dBh1 = dBh0 + 64;
    short8v* const dBl0 = Bs_lo + w * 128;      short8v* const dBl1 = dBl0 + 64;

    // ---- ds_read fragment indices (loop-invariant, swizzle-matched) ----
    const int lc = lane & 15;          // row-in-frag
    const int lk = lane >> 4;          // 16B k-slot
    int ia[4], ib[4];
    #pragma unroll
    for (int m = 0; m < 4; ++m) { const int r = wm + m * 16 + lc; ia[m] = r * 4 + (lk ^ ((r >> 1) & 3)); }
    #pragma unroll
    for (int n = 0; n < 4; ++n) { const int r = wn + n * 16 + lc; ib[n] = r * 4 + (lk ^ ((r >> 1) & 3)); }

    f32x4 acc[4][4];
    #pragma unroll
    for (int m = 0; m < 4; ++m)
        #pragma unroll
        for (int n = 0; n < 4; ++n) acc[m][n] = (f32x4)(0.f);

    // ---- prologue: stage K-tile 0 into buffer 0 ----
    gld16(pAhi + aoff0, dAh0);  gld16(pAhi + aoff1, dAh1);
    gld16(pAlo + aoff0, dAl0);  gld16(pAlo + aoff1, dAl1);
    gld16(pBhi + boff0, dBh0);  gld16(pBhi + boff1, dBh1);
    gld16(pBlo + boff0, dBl0);  gld16(pBlo + boff1, dBl1);
    __syncthreads();

    #pragma unroll 2
    for (int t = 0; t < 24; ++t) {
        const int cof = (t & 1) << 9;            // current buffer slot offset
        if (t < 23) {
            const int nof = ((t & 1) ^ 1) << 9;  // next buffer
            const int kk2 = (t + 1) * 64;        // byte offset along K
            gld16(pAhi + aoff0 + kk2, dAh0 + nof);
            gld16(pAhi + aoff1 + kk2, dAh1 + nof);
            gld16(pAlo + aoff0 + kk2, dAl0 + nof);
            gld16(pAlo + aoff1 + kk2, dAl1 + nof);
            gld16(pBhi + boff0 + kk2, dBh0 + nof);
            gld16(pBhi + boff1 + kk2, dBh1 + nof);
            gld16(pBlo + boff0 + kk2, dBl0 + nof);
            gld16(pBlo + boff1 + kk2, dBl1 + nof);
        }

        short8v ah[4], al[4], bh[4], bl[4];
        #pragma unroll
        for (int m = 0; m < 4; ++m) { ah[m] = As_hi[cof + ia[m]]; al[m] = As_lo[cof + ia[m]]; }
        #pragma unroll
        for (int n = 0; n < 4; ++n) { bh[n] = Bs_hi[cof + ib[n]]; bl[n] = Bs_lo[cof + ib[n]]; }

        #pragma unroll
        for (int m = 0; m < 4; ++m)
            #pragma unroll
            for (int n = 0; n < 4; ++n) {
                acc[m][n] = __builtin_amdgcn_mfma_f32_16x16x32_bf16(ah[m], bh[n], acc[m][n], 0, 0, 0);
                acc[m][n] = __builtin_amdgcn_mfma_f32_16x16x32_bf16(ah[m], bl[n], acc[m][n], 0, 0, 0);
                acc[m][n] = __builtin_amdgcn_mfma_f32_16x16x32_bf16(al[m], bh[n], acc[m][n], 0, 0, 0);
            }
        // one barrier per K-step: waves done reading buf[cur] (lgkm drained
        // before MFMA use), and __syncthreads' vmcnt drain publishes the
        // prefetched buf[cur^1] LDS writes for the next iteration.
        __syncthreads();
    }

    // ---- epilogue: C/D layout col=lane&15, row=(lane>>4)*4+reg (m89) ----
    const int erow = lane >> 4;
    #pragma unroll
    for (int m = 0; m < 4; ++m) {
        #pragma unroll
        for (int n = 0; n < 4; ++n) {
            const int gcol = n0 + wn + n * 16 + lc;
            const float bv = bias[gcol];
            const int grow0 = m0 + wm + m * 16 + erow * 4;
            #pragma unroll
            for (int r = 0; r < 4; ++r) {
                float v = acc[m][n][r] + bv;
                const size_t o = (size_t)(grow0 + r) * D_DIM + gcol;
                if (MODE == 0) {
                    v = fmaxf(v, 0.f);
                    unsigned short h, l; split2(v, h, l);
                    out_hi[o] = h; out_lo[o] = l;
                } else {
                    out_f[o] = v + resid[o];
                }
            }
        }
    }
}

// ---------------------------------------------------------------------------
// LayerNorm: reads x[M,768] fp32, writes ff as bf16 + rnorm[m].
// One wave per row, 4 rows per block.
// ---------------------------------------------------------------------------
__global__ __launch_bounds__(256)
void ln_kernel(const float* __restrict__ x, const float* __restrict__ gamma,
               const float* __restrict__ beta, unsigned short* __restrict__ ffb,
               float* __restrict__ rnorm)
{
    const int wave = threadIdx.x >> 6;
    const int lane = threadIdx.x & 63;
    const int row  = blockIdx.x * 4 + wave;
    const float* xr = x + (size_t)row * D_DIM;
    unsigned short* fr = ffb + (size_t)row * D_DIM;

    float v[12];
    float sum = 0.f, sumsq = 0.f;
    #pragma unroll
    for (int j = 0; j < 3; ++j) {
        const float4 f = *reinterpret_cast<const float4*>(&xr[j * 256 + lane * 4]);
        v[j * 4 + 0] = f.x; v[j * 4 + 1] = f.y; v[j * 4 + 2] = f.z; v[j * 4 + 3] = f.w;
    }
    #pragma unroll
    for (int e = 0; e < 12; ++e) { sum += v[e]; sumsq = fmaf(v[e], v[e], sumsq); }
    #pragma unroll
    for (int m = 1; m < 64; m <<= 1) {
        sum   += __shfl_xor(sum, m);
        sumsq += __shfl_xor(sumsq, m);
    }
    const float mean = sum * (1.f / 768.f);
    const float var  = sumsq * (1.f / 768.f) - mean * mean;
    const float rstd = 1.f / sqrtf(var + LN_EPS);

    float nsq = 0.f;
    #pragma unroll
    for (int j = 0; j < 3; ++j) {
        const int c = j * 256 + lane * 4;
        const float4 g  = *reinterpret_cast<const float4*>(&gamma[c]);
        const float4 bt = *reinterpret_cast<const float4*>(&beta[c]);
        float4 o;
        o.x = fmaf(g.x * (v[j*4+0] - mean), rstd, bt.x);
        o.y = fmaf(g.y * (v[j*4+1] - mean), rstd, bt.y);
        o.z = fmaf(g.z * (v[j*4+2] - mean), rstd, bt.z);
        o.w = fmaf(g.w * (v[j*4+3] - mean), rstd, bt.w);
        nsq = fmaf(o.x, o.x, nsq); nsq = fmaf(o.y, o.y, nsq);
        nsq = fmaf(o.z, o.z, nsq); nsq = fmaf(o.w, o.w, nsq);
        ushort4 ob;
        ob.x = f2bf(o.x); ob.y = f2bf(o.y); ob.z = f2bf(o.z); ob.w = f2bf(o.w);
        *reinterpret_cast<ushort4*>(&fr[c]) = ob;
    }
    #pragma unroll
    for (int m = 1; m < 64; m <<= 1) nsq += __shfl_xor(nsq, m);
    if (lane == 0) rnorm[row] = 1.f / fmaxf(sqrtf(nsq), COS_EPS);
}

__global__ void zero_kernel(float* __restrict__ p, int n)
{
    const int i = blockIdx.x * 256 + threadIdx.x;
    if (i < n) p[i] = 0.f;
}

// ---------------------------------------------------------------------------
// s[b][d] = sum_l ff[b][l][d] * rnorm[b][l]  (bf16 ff; partial per L-quarter)
// ---------------------------------------------------------------------------
__global__ __launch_bounds__(256)
void colsum_kernel(const unsigned short* __restrict__ ffb, const float* __restrict__ rnorm,
                   float* __restrict__ s)
{
    const int c = blockIdx.x * 256 + threadIdx.x;
    const int q = blockIdx.y;
    const int b = blockIdx.z;
    const unsigned short* fb = ffb + (size_t)b * L_DIM * D_DIM;
    const float* rb = rnorm + b * L_DIM;
    float acc = 0.f;
    #pragma unroll 4
    for (int l = q * 128; l < q * 128 + 128; ++l)
        acc = fmaf(bf2f(fb[(size_t)l * D_DIM + c]), rb[l], acc);
    atomicAdd(&s[b * D_DIM + c], acc);
}

// ---------------------------------------------------------------------------
// Per-row epilogue: out1 = ff@Wy + by, out2 = ff@Wz + bz,
// aw_raw = 1/(1+exp(ff.s * rnorm / L)). One wave per row. bf16 ff loads.
// ---------------------------------------------------------------------------
__global__ __launch_bounds__(256)
void rowout_kernel(const unsigned short* __restrict__ ffb, const float* __restrict__ rnorm,
                   const float* __restrict__ s,
                   const float* __restrict__ Wy, const float* __restrict__ by,
                   const float* __restrict__ Wz, const float* __restrict__ bz,
                   float* __restrict__ out1, float* __restrict__ out2,
                   float* __restrict__ aw)
{
    const int wave = threadIdx.x >> 6;
    const int lane = threadIdx.x & 63;
    const int row  = blockIdx.x * 4 + wave;
    const int b    = row >> 9;
    const unsigned short* fr = ffb + (size_t)row * D_DIM;
    const float* sb = s + b * D_DIM;

    float ds = 0.f;
    float dy[YD] = {0.f, 0.f, 0.f};
    float dz[ZD] = {0.f, 0.f, 0.f, 0.f, 0.f};
    #pragma unroll
    for (int j = 0; j < 3; ++j) {
        const int c = j * 256 + lane * 4;
        const ushort4 fb4 = *reinterpret_cast<const ushort4*>(&fr[c]);
        const float4 sv = *reinterpret_cast<const float4*>(&sb[c]);
        const float fe[4] = {bf2f(fb4.x), bf2f(fb4.y), bf2f(fb4.z), bf2f(fb4.w)};
        const float se[4] = {sv.x, sv.y, sv.z, sv.w};
        #pragma unroll
        for (int e = 0; e < 4; ++e) {
            const int col = c + e;
            ds = fmaf(fe[e], se[e], ds);
            #pragma unroll
            for (int y = 0; y < YD; ++y) dy[y] = fmaf(fe[e], Wy[col * YD + y], dy[y]);
            #pragma unroll
            for (int z = 0; z < ZD; ++z) dz[z] = fmaf(fe[e], Wz[col * ZD + z], dz[z]);
        }
    }
    #pragma unroll
    for (int m = 1; m < 64; m <<= 1) {
        ds += __shfl_xor(ds, m);
        #pragma unroll
        for (int y = 0; y < YD; ++y) dy[y] += __shfl_xor(dy[y], m);
        #pragma unroll
        for (int z = 0; z < ZD; ++z) dz[z] += __shfl_xor(dz[z], m);
    }
    if (lane == 0) {
        const float a = ds * rnorm[row] * (1.f / (float)L_DIM);
        aw[row] = 1.f / (1.f + expf(a));
        #pragma unroll
        for (int y = 0; y < YD; ++y) out1[(size_t)row * YD + y] = dy[y] + by[y];
        #pragma unroll
        for (int z = 0; z < ZD; ++z) out2[(size_t)row * ZD + z] = dz[z] + bz[z];
    }
}

__global__ __launch_bounds__(512)
void softmax_kernel(const float* __restrict__ aw, float* __restrict__ attn)
{
    __shared__ float red[8];
    const int b = blockIdx.x;
    const int t = threadIdx.x;
    const int wave = t >> 6, lane = t & 63;
    const float v = aw[b * L_DIM + t];

    float mx = v;
    #pragma unroll
    for (int m = 1; m < 64; m <<= 1) mx = fmaxf(mx, __shfl_xor(mx, m));
    if (lane == 0) red[wave] = mx;
    __syncthreads();
    mx = red[0];
    #pragma unroll
    for (int w = 1; w < 8; ++w) mx = fmaxf(mx, red[w]);
    __syncthreads();

    const float e = expf(v - mx);
    float sm = e;
    #pragma unroll
    for (int m = 1; m < 64; m <<= 1) sm += __shfl_xor(sm, m);
    if (lane == 0) red[wave] = sm;
    __syncthreads();
    float tot = 0.f;
    #pragma unroll
    for (int w = 0; w < 8; ++w) tot += red[w];

    attn[b * L_DIM + t] = e / tot;
}

// ---------------------------------------------------------------------------
extern "C" void kernel_launch(void* const* d_in, const int* in_sizes, int n_in,
                              void* d_out, int out_size, void* d_ws, size_t ws_size,
                              hipStream_t stream)
{
    const float* emb   = (const float*)d_in[0];
    const float* W1    = (const float*)d_in[1];
    const float* b1    = (const float*)d_in[2];
    const float* W2    = (const float*)d_in[3];
    const float* b2    = (const float*)d_in[4];
    const float* gamma = (const float*)d_in[5];
    const float* beta  = (const float*)d_in[6];
    const float* Wy    = (const float*)d_in[7];
    const float* by    = (const float*)d_in[8];
    const float* Wz    = (const float*)d_in[9];
    const float* bz    = (const float*)d_in[10];

    float* out = (float*)d_out;
    char*  p   = (char*)d_ws;

    const size_t MD = (size_t)M_DIM * D_DIM;

    unsigned short* h1_hi = (unsigned short*)p;  p += MD * 2;
    unsigned short* h1_lo = (unsigned short*)p;  p += MD * 2;
    // emb-split region aliases xf: emb_hi/lo dead after GEMM1; GEMM2 writes xf here
    float*          xf     = (float*)p;
    unsigned short* emb_hi = (unsigned short*)p;
    unsigned short* emb_lo = emb_hi + MD;        p += MD * 4;
    unsigned short* w1t_hi = (unsigned short*)p; p += (size_t)D_DIM * D_DIM * 2;
    unsigned short* w1t_lo = (unsigned short*)p; p += (size_t)D_DIM * D_DIM * 2;
    unsigned short* w2t_hi = (unsigned short*)p; p += (size_t)D_DIM * D_DIM * 2;
    unsigned short* w2t_lo = (unsigned short*)p; p += (size_t)D_DIM * D_DIM * 2;
    float* rnorm = (float*)p;                    p += (size_t)M_DIM * 4;
    float* awb   = (float*)p;                    p += (size_t)M_DIM * 4;
    float* s     = (float*)p;

    // ff (bf16) aliases h1_hi: h1 hi/lo are dead after GEMM2 completes.
    unsigned short* ffb = h1_hi;

    float* out1 = out;
    float* out2 = out + (size_t)M_DIM * YD;
    float* attn = out + (size_t)M_DIM * (YD + ZD);

    split_kernel<<<(int)(MD / 4 / 256), 256, 0, stream>>>(emb, emb_hi, emb_lo, (int)(MD / 4));
    tsplit_kernel<<<dim3(24, 24), 256, 0, stream>>>(W1, w1t_hi, w1t_lo);
    tsplit_kernel<<<dim3(24, 24), 256, 0, stream>>>(W2, w2t_hi, w2t_lo);

    const dim3 gg(D_DIM / 128, M_DIM / 128);     // (6, 256) = 1536 wgs, %8==0
    gemm_mfma<0><<<gg, 256, 0, stream>>>(emb_hi, emb_lo, w1t_hi, w1t_lo, b1, nullptr,
                                         h1_hi, h1_lo, nullptr);
    gemm_mfma<1><<<gg, 256, 0, stream>>>(h1_hi, h1_lo, w2t_hi, w2t_lo, b2, emb,
                                         nullptr, nullptr, xf);

    ln_kernel<<<M_DIM / 4, 256, 0, stream>>>(xf, gamma, beta, ffb, rnorm);
    zero_kernel<<<(B_DIM * D_DIM + 255) / 256, 256, 0, stream>>>(s, B_DIM * D_DIM);
    colsum_kernel<<<dim3(3, 4, B_DIM), 256, 0, stream>>>(ffb, rnorm, s);
    rowout_kernel<<<M_DIM / 4, 256, 0, stream>>>(ffb, rnorm, s, Wy, by, Wz, bz,
                                                 out1, out2, awb);
    softmax_kernel<<<B_DIM, 512, 0, stream>>>(awb, attn);
}

// Round 6
// 501.882 us; speedup vs baseline: 1.0421x; 1.0421x over previous
//
#include <hip/hip_runtime.h>
#include <hip/hip_bf16.h>
#include <math.h>

#define D_DIM 768
#define B_DIM 64
#define L_DIM 512
#define M_DIM (B_DIM * L_DIM)   /* 32768 rows */
#define YD 3
#define ZD 5
#define LN_EPS 1e-5f
#define COS_EPS 1e-8f

typedef short short8v __attribute__((ext_vector_type(8)));
typedef float f32x4  __attribute__((ext_vector_type(4)));

// ---------------------------------------------------------------------------
// bf16 helpers (RNE), split x = hi + lo with hi,lo bf16; |err| <= 2^-17 |x|
// ---------------------------------------------------------------------------
__device__ __forceinline__ unsigned short f2bf(float f) {
    unsigned u = __builtin_bit_cast(unsigned, f);
    u = (u + 0x7fffu + ((u >> 16) & 1u)) >> 16;
    return (unsigned short)u;
}
__device__ __forceinline__ float bf2f(unsigned short h) {
    unsigned u = ((unsigned)h) << 16;
    return __builtin_bit_cast(float, u);
}
__device__ __forceinline__ void split2(float v, unsigned short& h, unsigned short& l) {
    h = f2bf(v);
    l = f2bf(v - bf2f(h));
}

// async global->LDS, 16B per lane, wave-uniform LDS base + lane*16
__device__ __forceinline__ void gld16(const void* g, void* l) {
    __builtin_amdgcn_global_load_lds(
        (const __attribute__((address_space(1))) void*)g,
        (__attribute__((address_space(3))) void*)l, 16, 0, 0);
}

// ---------------------------------------------------------------------------
// W[768][768] -> Wt_hi/Wt_lo[n][k] (transposed, split). 32x32 LDS tiles.
// ---------------------------------------------------------------------------
__global__ __launch_bounds__(256)
void tsplit_kernel(const float* __restrict__ W, unsigned short* __restrict__ thi,
                   unsigned short* __restrict__ tlo)
{
    __shared__ float t[32][33];
    const int tx = threadIdx.x & 31, ty = threadIdx.x >> 5;
    const int n0 = blockIdx.x * 32, k0 = blockIdx.y * 32;
    #pragma unroll
    for (int j = 0; j < 4; ++j)
        t[ty + 8 * j][tx] = W[(size_t)(k0 + ty + 8 * j) * D_DIM + n0 + tx];
    __syncthreads();
    #pragma unroll
    for (int j = 0; j < 4; ++j) {
        const float v = t[tx][ty + 8 * j];
        unsigned short h, l; split2(v, h, l);
        const size_t o = (size_t)(n0 + ty + 8 * j) * D_DIM + k0 + tx;
        thi[o] = h; tlo[o] = l;
    }
}

// ---------------------------------------------------------------------------
// MFMA GEMM: out[M,768] = epilogue( (Ahi+Alo) @ (Bhi+Blo)^T' + bias )
//   3-term split product: Ahi*Bhi + Ahi*Blo + Alo*Bhi  (fp32 acc, 16x16x32)
// MODE 0 (GEMM1): A = fp32 emb, split hi/lo IN-KERNEL during staging
//                 (reg->ds_write path; eliminates the standalone split pass).
//                 epilogue: relu -> write split bf16 hi/lo.
// MODE 1 (GEMM2): A = pre-split hi/lo via global_load_lds.
//                 epilogue: + bias + resid -> fp32.
// 128x128 tile, BK=32, 256 thr (4 waves 2x2), wave tile 64x64 (4x4 frags).
// Single-buffer 2-barrier loop (R4-proven; dbuf regressed occupancy in R5).
// T1 XCD swizzle (1536 wgs %8==0). LDS slot XOR-swizzle on BOTH the write
// side (pre-swizzled gld source / swizzled ds_write index) and ds_read (G21).
// ---------------------------------------------------------------------------
template<int MODE>
__global__ __launch_bounds__(256, 2)
void gemm_mfma(const float* __restrict__ Af,
               const unsigned short* __restrict__ Ahi, const unsigned short* __restrict__ Alo,
               const unsigned short* __restrict__ Bhi, const unsigned short* __restrict__ Blo,
               const float* __restrict__ bias, const float* __restrict__ resid,
               unsigned short* __restrict__ out_hi, unsigned short* __restrict__ out_lo,
               float* __restrict__ out_f)
{
    __shared__ short8v As_hi[512], As_lo[512], Bs_hi[512], Bs_lo[512]; // 4 x 8KB

    // ---- XCD-aware swizzle: lin -> lid, then (bx,by) ----
    const int lin = blockIdx.y * gridDim.x + blockIdx.x;     // hw linear id
    const int cpx = (gridDim.x * gridDim.y) >> 3;            // 192
    const int lid = (lin & 7) * cpx + (lin >> 3);
    const int bx  = lid % 6;
    const int by  = lid / 6;

    const int tid  = threadIdx.x;
    const int w    = tid >> 6;
    const int lane = tid & 63;
    const int m0   = by * 128;
    const int n0   = bx * 128;
    const int wm   = (w >> 1) * 64;     // wave tile origin in block
    const int wn   = (w & 1) * 64;

    // ---- B staging (gld16, pre-swizzled global source, m173) ----
    const int rr = lane >> 2;          // row-within-1KB-chunk
    const int cc = lane & 3;           // 16B slot
    const int r0 = w * 32 + rr;        // chunk q=0 row (0..127)
    const int r1 = r0 + 16;            // chunk q=1 row
    const int sw0 = (cc ^ ((r0 >> 1) & 3)) * 16;   // swizzled byte-slot in row
    const int sw1 = (cc ^ ((r1 >> 1) & 3)) * 16;
    const size_t boff0 = (size_t)(n0 + r0) * 1536 + sw0;  // 768*2B row stride
    const size_t boff1 = (size_t)(n0 + r1) * 1536 + sw1;
    const char* pBhi = (const char*)Bhi; const char* pBlo = (const char*)Blo;
    short8v* const dBh0 = Bs_hi + w * 128;      short8v* const dBh1 = dBh0 + 64;
    short8v* const dBl0 = Bs_lo + w * 128;      short8v* const dBl1 = dBl0 + 64;

    // ---- A staging: MODE1 gld16 path ----
    const size_t aoff0 = (size_t)(m0 + r0) * 1536 + sw0;
    const size_t aoff1 = (size_t)(m0 + r1) * 1536 + sw1;
    const char* pAhi = (const char*)Ahi; const char* pAlo = (const char*)Alo;
    short8v* const dAh0 = As_hi + w * 128;      short8v* const dAh1 = dAh0 + 64;
    short8v* const dAl0 = As_lo + w * 128;      short8v* const dAl1 = dAl0 + 64;

    // ---- A staging: MODE0 fp32-split path (thread -> row, k-half) ----
    const int ar  = tid >> 1;                  // 0..127
    const int ak0 = (tid & 1) * 16;            // k-offset 0 or 16
    const int asw = (ar >> 1) & 3;
    const int sA0 = ar * 4 + (((tid & 1) * 2 + 0) ^ asw);  // slot idx for k [ak0, ak0+8)
    const int sA1 = ar * 4 + (((tid & 1) * 2 + 1) ^ asw);  // slot idx for k [ak0+8, ak0+16)
    const float* gA = (MODE == 0) ? (Af + (size_t)(m0 + ar) * D_DIM + ak0) : nullptr;

    // ---- ds_read fragment indices (loop-invariant, swizzle-matched) ----
    const int lc = lane & 15;          // row-in-frag
    const int lk = lane >> 4;          // 16B k-slot
    int ia[4], ib[4];
    #pragma unroll
    for (int m = 0; m < 4; ++m) { const int r = wm + m * 16 + lc; ia[m] = r * 4 + (lk ^ ((r >> 1) & 3)); }
    #pragma unroll
    for (int n = 0; n < 4; ++n) { const int r = wn + n * 16 + lc; ib[n] = r * 4 + (lk ^ ((r >> 1) & 3)); }

    f32x4 acc[4][4];
    #pragma unroll
    for (int m = 0; m < 4; ++m)
        #pragma unroll
        for (int n = 0; n < 4; ++n) acc[m][n] = (f32x4)(0.f);

    for (int t = 0; t < 24; ++t) {
        const int kk2 = t * 64;                // byte offset along K (bf16)
        // ---- B stage ----
        gld16(pBhi + boff0 + kk2, dBh0);
        gld16(pBhi + boff1 + kk2, dBh1);
        gld16(pBlo + boff0 + kk2, dBl0);
        gld16(pBlo + boff1 + kk2, dBl1);
        // ---- A stage ----
        if (MODE == 0) {
            const int kk = t * 32;             // element offset (fp32)
            float tmp[16];
            #pragma unroll
            for (int q = 0; q < 4; ++q) {
                const float4 f = *reinterpret_cast<const float4*>(gA + kk + q * 4);
                tmp[q * 4 + 0] = f.x; tmp[q * 4 + 1] = f.y;
                tmp[q * 4 + 2] = f.z; tmp[q * 4 + 3] = f.w;
            }
            short8v h0, h1, l0, l1;
            #pragma unroll
            for (int e = 0; e < 8; ++e) {
                unsigned short h, l;
                split2(tmp[e], h, l);     h0[e] = (short)h; l0[e] = (short)l;
                split2(tmp[8 + e], h, l); h1[e] = (short)h; l1[e] = (short)l;
            }
            As_hi[sA0] = h0; As_hi[sA1] = h1;
            As_lo[sA0] = l0; As_lo[sA1] = l1;
        } else {
            gld16(pAhi + aoff0 + kk2, dAh0);
            gld16(pAhi + aoff1 + kk2, dAh1);
            gld16(pAlo + aoff0 + kk2, dAl0);
            gld16(pAlo + aoff1 + kk2, dAl1);
        }
        __syncthreads();   // drains vmcnt+lgkm: staged tile visible to all

        short8v ah[4], al[4], bh[4], bl[4];
        #pragma unroll
        for (int m = 0; m < 4; ++m) { ah[m] = As_hi[ia[m]]; al[m] = As_lo[ia[m]]; }
        #pragma unroll
        for (int n = 0; n < 4; ++n) { bh[n] = Bs_hi[ib[n]]; bl[n] = Bs_lo[ib[n]]; }

        #pragma unroll
        for (int m = 0; m < 4; ++m)
            #pragma unroll
            for (int n = 0; n < 4; ++n) {
                acc[m][n] = __builtin_amdgcn_mfma_f32_16x16x32_bf16(ah[m], bh[n], acc[m][n], 0, 0, 0);
                acc[m][n] = __builtin_amdgcn_mfma_f32_16x16x32_bf16(ah[m], bl[n], acc[m][n], 0, 0, 0);
                acc[m][n] = __builtin_amdgcn_mfma_f32_16x16x32_bf16(al[m], bh[n], acc[m][n], 0, 0, 0);
            }
        __syncthreads();   // protect LDS before next stage
    }

    // ---- epilogue: C/D layout col=lane&15, row=(lane>>4)*4+reg (m89) ----
    const int erow = lane >> 4;
    #pragma unroll
    for (int m = 0; m < 4; ++m) {
        #pragma unroll
        for (int n = 0; n < 4; ++n) {
            const int gcol = n0 + wn + n * 16 + lc;
            const float bv = bias[gcol];
            const int grow0 = m0 + wm + m * 16 + erow * 4;
            #pragma unroll
            for (int r = 0; r < 4; ++r) {
                float v = acc[m][n][r] + bv;
                const size_t o = (size_t)(grow0 + r) * D_DIM + gcol;
                if (MODE == 0) {
                    v = fmaxf(v, 0.f);
                    unsigned short h, l; split2(v, h, l);
                    out_hi[o] = h; out_lo[o] = l;
                } else {
                    out_f[o] = v + resid[o];
                }
            }
        }
    }
}

// ---------------------------------------------------------------------------
// LayerNorm: reads x[M,768] fp32, writes ff as bf16 + rnorm[m].
// One wave per row, 4 rows per block.
// ---------------------------------------------------------------------------
__global__ __launch_bounds__(256)
void ln_kernel(const float* __restrict__ x, const float* __restrict__ gamma,
               const float* __restrict__ beta, unsigned short* __restrict__ ffb,
               float* __restrict__ rnorm)
{
    const int wave = threadIdx.x >> 6;
    const int lane = threadIdx.x & 63;
    const int row  = blockIdx.x * 4 + wave;
    const float* xr = x + (size_t)row * D_DIM;
    unsigned short* fr = ffb + (size_t)row * D_DIM;

    float v[12];
    float sum = 0.f, sumsq = 0.f;
    #pragma unroll
    for (int j = 0; j < 3; ++j) {
        const float4 f = *reinterpret_cast<const float4*>(&xr[j * 256 + lane * 4]);
        v[j * 4 + 0] = f.x; v[j * 4 + 1] = f.y; v[j * 4 + 2] = f.z; v[j * 4 + 3] = f.w;
    }
    #pragma unroll
    for (int e = 0; e < 12; ++e) { sum += v[e]; sumsq = fmaf(v[e], v[e], sumsq); }
    #pragma unroll
    for (int m = 1; m < 64; m <<= 1) {
        sum   += __shfl_xor(sum, m);
        sumsq += __shfl_xor(sumsq, m);
    }
    const float mean = sum * (1.f / 768.f);
    const float var  = sumsq * (1.f / 768.f) - mean * mean;
    const float rstd = 1.f / sqrtf(var + LN_EPS);

    float nsq = 0.f;
    #pragma unroll
    for (int j = 0; j < 3; ++j) {
        const int c = j * 256 + lane * 4;
        const float4 g  = *reinterpret_cast<const float4*>(&gamma[c]);
        const float4 bt = *reinterpret_cast<const float4*>(&beta[c]);
        float4 o;
        o.x = fmaf(g.x * (v[j*4+0] - mean), rstd, bt.x);
        o.y = fmaf(g.y * (v[j*4+1] - mean), rstd, bt.y);
        o.z = fmaf(g.z * (v[j*4+2] - mean), rstd, bt.z);
        o.w = fmaf(g.w * (v[j*4+3] - mean), rstd, bt.w);
        nsq = fmaf(o.x, o.x, nsq); nsq = fmaf(o.y, o.y, nsq);
        nsq = fmaf(o.z, o.z, nsq); nsq = fmaf(o.w, o.w, nsq);
        ushort4 ob;
        ob.x = f2bf(o.x); ob.y = f2bf(o.y); ob.z = f2bf(o.z); ob.w = f2bf(o.w);
        *reinterpret_cast<ushort4*>(&fr[c]) = ob;
    }
    #pragma unroll
    for (int m = 1; m < 64; m <<= 1) nsq += __shfl_xor(nsq, m);
    if (lane == 0) rnorm[row] = 1.f / fmaxf(sqrtf(nsq), COS_EPS);
}

// ---------------------------------------------------------------------------
// s_part[b][q][d] = sum_{l in quarter q} ff[b][l][d] * rnorm[b][l]
// No atomics, no zero-init. grid (3, 4, 64), 256 threads.
// ---------------------------------------------------------------------------
__global__ __launch_bounds__(256)
void colsum_kernel(const unsigned short* __restrict__ ffb, const float* __restrict__ rnorm,
                   float* __restrict__ s_part)
{
    const int c = blockIdx.x * 256 + threadIdx.x;
    const int q = blockIdx.y;
    const int b = blockIdx.z;
    const unsigned short* fb = ffb + (size_t)b * L_DIM * D_DIM;
    const float* rb = rnorm + b * L_DIM;
    float acc = 0.f;
    #pragma unroll 4
    for (int l = q * 128; l < q * 128 + 128; ++l)
        acc = fmaf(bf2f(fb[(size_t)l * D_DIM + c]), rb[l], acc);
    s_part[((size_t)b * 4 + q) * D_DIM + c] = acc;
}

// ---------------------------------------------------------------------------
// Per-row epilogue: out1 = ff@Wy + by, out2 = ff@Wz + bz,
// aw_raw = 1/(1+exp(ff.s * rnorm / L)). One wave per row. bf16 ff loads.
// s = sum of 4 quarter-partials (L2/L3 resident).
// ---------------------------------------------------------------------------
__global__ __launch_bounds__(256)
void rowout_kernel(const unsigned short* __restrict__ ffb, const float* __restrict__ rnorm,
                   const float* __restrict__ s_part,
                   const float* __restrict__ Wy, const float* __restrict__ by,
                   const float* __restrict__ Wz, const float* __restrict__ bz,
                   float* __restrict__ out1, float* __restrict__ out2,
                   float* __restrict__ aw)
{
    const int wave = threadIdx.x >> 6;
    const int lane = threadIdx.x & 63;
    const int row  = blockIdx.x * 4 + wave;
    const int b    = row >> 9;
    const unsigned short* fr = ffb + (size_t)row * D_DIM;
    const float* sb = s_part + (size_t)b * 4 * D_DIM;

    float ds = 0.f;
    float dy[YD] = {0.f, 0.f, 0.f};
    float dz[ZD] = {0.f, 0.f, 0.f, 0.f, 0.f};
    #pragma unroll
    for (int j = 0; j < 3; ++j) {
        const int c = j * 256 + lane * 4;
        const ushort4 fb4 = *reinterpret_cast<const ushort4*>(&fr[c]);
        const float4 s0 = *reinterpret_cast<const float4*>(&sb[c]);
        const float4 s1 = *reinterpret_cast<const float4*>(&sb[D_DIM + c]);
        const float4 s2 = *reinterpret_cast<const float4*>(&sb[2 * D_DIM + c]);
        const float4 s3 = *reinterpret_cast<const float4*>(&sb[3 * D_DIM + c]);
        const float fe[4] = {bf2f(fb4.x), bf2f(fb4.y), bf2f(fb4.z), bf2f(fb4.w)};
        const float se[4] = {s0.x + s1.x + s2.x + s3.x,
                             s0.y + s1.y + s2.y + s3.y,
                             s0.z + s1.z + s2.z + s3.z,
                             s0.w + s1.w + s2.w + s3.w};
        #pragma unroll
        for (int e = 0; e < 4; ++e) {
            const int col = c + e;
            ds = fmaf(fe[e], se[e], ds);
            #pragma unroll
            for (int y = 0; y < YD; ++y) dy[y] = fmaf(fe[e], Wy[col * YD + y], dy[y]);
            #pragma unroll
            for (int z = 0; z < ZD; ++z) dz[z] = fmaf(fe[e], Wz[col * ZD + z], dz[z]);
        }
    }
    #pragma unroll
    for (int m = 1; m < 64; m <<= 1) {
        ds += __shfl_xor(ds, m);
        #pragma unroll
        for (int y = 0; y < YD; ++y) dy[y] += __shfl_xor(dy[y], m);
        #pragma unroll
        for (int z = 0; z < ZD; ++z) dz[z] += __shfl_xor(dz[z], m);
    }
    if (lane == 0) {
        const float a = ds * rnorm[row] * (1.f / (float)L_DIM);
        aw[row] = 1.f / (1.f + expf(a));
        #pragma unroll
        for (int y = 0; y < YD; ++y) out1[(size_t)row * YD + y] = dy[y] + by[y];
        #pragma unroll
        for (int z = 0; z < ZD; ++z) out2[(size_t)row * ZD + z] = dz[z] + bz[z];
    }
}

__global__ __launch_bounds__(512)
void softmax_kernel(const float* __restrict__ aw, float* __restrict__ attn)
{
    __shared__ float red[8];
    const int b = blockIdx.x;
    const int t = threadIdx.x;
    const int wave = t >> 6, lane = t & 63;
    const float v = aw[b * L_DIM + t];

    float mx = v;
    #pragma unroll
    for (int m = 1; m < 64; m <<= 1) mx = fmaxf(mx, __shfl_xor(mx, m));
    if (lane == 0) red[wave] = mx;
    __syncthreads();
    mx = red[0];
    #pragma unroll
    for (int w = 1; w < 8; ++w) mx = fmaxf(mx, red[w]);
    __syncthreads();

    const float e = expf(v - mx);
    float sm = e;
    #pragma unroll
    for (int m = 1; m < 64; m <<= 1) sm += __shfl_xor(sm, m);
    if (lane == 0) red[wave] = sm;
    __syncthreads();
    float tot = 0.f;
    #pragma unroll
    for (int w = 0; w < 8; ++w) tot += red[w];

    attn[b * L_DIM + t] = e / tot;
}

// ---------------------------------------------------------------------------
extern "C" void kernel_launch(void* const* d_in, const int* in_sizes, int n_in,
                              void* d_out, int out_size, void* d_ws, size_t ws_size,
                              hipStream_t stream)
{
    const float* emb   = (const float*)d_in[0];
    const float* W1    = (const float*)d_in[1];
    const float* b1    = (const float*)d_in[2];
    const float* W2    = (const float*)d_in[3];
    const float* b2    = (const float*)d_in[4];
    const float* gamma = (const float*)d_in[5];
    const float* beta  = (const float*)d_in[6];
    const float* Wy    = (const float*)d_in[7];
    const float* by    = (const float*)d_in[8];
    const float* Wz    = (const float*)d_in[9];
    const float* bz    = (const float*)d_in[10];

    float* out = (float*)d_out;
    char*  p   = (char*)d_ws;

    const size_t MD = (size_t)M_DIM * D_DIM;

    unsigned short* h1_hi = (unsigned short*)p;  p += MD * 2;
    unsigned short* h1_lo = (unsigned short*)p;  p += MD * 2;
    float*          xf    = (float*)p;           p += MD * 4;
    unsigned short* w1t_hi = (unsigned short*)p; p += (size_t)D_DIM * D_DIM * 2;
    unsigned short* w1t_lo = (unsigned short*)p; p += (size_t)D_DIM * D_DIM * 2;
    unsigned short* w2t_hi = (unsigned short*)p; p += (size_t)D_DIM * D_DIM * 2;
    unsigned short* w2t_lo = (unsigned short*)p; p += (size_t)D_DIM * D_DIM * 2;
    float* rnorm  = (float*)p;                   p += (size_t)M_DIM * 4;
    float* awb    = (float*)p;                   p += (size_t)M_DIM * 4;
    float* s_part = (float*)p;                   // B*4*D floats

    // ff (bf16) aliases h1_hi: h1 hi/lo are dead after GEMM2 completes.
    unsigned short* ffb = h1_hi;

    float* out1 = out;
    float* out2 = out + (size_t)M_DIM * YD;
    float* attn = out + (size_t)M_DIM * (YD + ZD);

    tsplit_kernel<<<dim3(24, 24), 256, 0, stream>>>(W1, w1t_hi, w1t_lo);
    tsplit_kernel<<<dim3(24, 24), 256, 0, stream>>>(W2, w2t_hi, w2t_lo);

    const dim3 gg(D_DIM / 128, M_DIM / 128);     // (6, 256) = 1536 wgs, %8==0
    gemm_mfma<0><<<gg, 256, 0, stream>>>(emb, nullptr, nullptr, w1t_hi, w1t_lo,
                                         b1, nullptr, h1_hi, h1_lo, nullptr);
    gemm_mfma<1><<<gg, 256, 0, stream>>>(nullptr, h1_hi, h1_lo, w2t_hi, w2t_lo,
                                         b2, emb, nullptr, nullptr, xf);

    ln_kernel<<<M_DIM / 4, 256, 0, stream>>>(xf, gamma, beta, ffb, rnorm);
    colsum_kernel<<<dim3(3, 4, B_DIM), 256, 0, stream>>>(ffb, rnorm, s_part);
    rowout_kernel<<<M_DIM / 4, 256, 0, stream>>>(ffb, rnorm, s_part, Wy, by, Wz, bz,
                                                 out1, out2, awb);
    softmax_kernel<<<B_DIM, 512, 0, stream>>>(awb, attn);
}

// Round 7
// 426.215 us; speedup vs baseline: 1.2272x; 1.1775x over previous
//
#include <hip/hip_runtime.h>
#include <hip/hip_bf16.h>
#include <math.h>

#define D_DIM 768
#define B_DIM 64
#define L_DIM 512
#define M_DIM (B_DIM * L_DIM)   /* 32768 rows */
#define YD 3
#define ZD 5
#define NCAT 16                  /* Wy(3) | Wz(5) | s(1) | pad(7) */
#define LN_EPS 1e-5f
#define COS_EPS 1e-8f

typedef short short8v __attribute__((ext_vector_type(8)));
typedef float f32x4  __attribute__((ext_vector_type(4)));

// ---------------------------------------------------------------------------
// bf16 helpers (RNE), split x = hi + lo with hi,lo bf16; |err| <= 2^-17 |x|
// ---------------------------------------------------------------------------
__device__ __forceinline__ unsigned short f2bf(float f) {
    unsigned u = __builtin_bit_cast(unsigned, f);
    u = (u + 0x7fffu + ((u >> 16) & 1u)) >> 16;
    return (unsigned short)u;
}
__device__ __forceinline__ float bf2f(unsigned short h) {
    unsigned u = ((unsigned)h) << 16;
    return __builtin_bit_cast(float, u);
}
__device__ __forceinline__ void split2(float v, unsigned short& h, unsigned short& l) {
    h = f2bf(v);
    l = f2bf(v - bf2f(h));
}

// async global->LDS, 16B per lane, wave-uniform LDS base + lane*16
__device__ __forceinline__ void gld16(const void* g, void* l) {
    __builtin_amdgcn_global_load_lds(
        (const __attribute__((address_space(1))) void*)g,
        (__attribute__((address_space(3))) void*)l, 16, 0, 0);
}

// ---------------------------------------------------------------------------
// W[768][768] -> Wt_hi/Wt_lo[n][k] (transposed, split). 32x32 LDS tiles.
// blockIdx.z selects W1 or W2 (merged launch).
// ---------------------------------------------------------------------------
__global__ __launch_bounds__(256)
void tsplit_kernel(const float* __restrict__ W1, const float* __restrict__ W2,
                   unsigned short* __restrict__ t1hi, unsigned short* __restrict__ t1lo,
                   unsigned short* __restrict__ t2hi, unsigned short* __restrict__ t2lo)
{
    const float* W = blockIdx.z ? W2 : W1;
    unsigned short* thi = blockIdx.z ? t2hi : t1hi;
    unsigned short* tlo = blockIdx.z ? t2lo : t1lo;
    __shared__ float t[32][33];
    const int tx = threadIdx.x & 31, ty = threadIdx.x >> 5;
    const int n0 = blockIdx.x * 32, k0 = blockIdx.y * 32;
    #pragma unroll
    for (int j = 0; j < 4; ++j)
        t[ty + 8 * j][tx] = W[(size_t)(k0 + ty + 8 * j) * D_DIM + n0 + tx];
    __syncthreads();
    #pragma unroll
    for (int j = 0; j < 4; ++j) {
        const float v = t[tx][ty + 8 * j];
        unsigned short h, l; split2(v, h, l);
        const size_t o = (size_t)(n0 + ty + 8 * j) * D_DIM + k0 + tx;
        thi[o] = h; tlo[o] = l;
    }
}

// ---------------------------------------------------------------------------
// MFMA GEMM: out[M,768] = epilogue( (Ahi+Alo) @ (Bhi+Blo)^T' + bias )
//   3-term split product: Ahi*Bhi + Ahi*Blo + Alo*Bhi  (fp32 acc, 16x16x32)
// MODE 0 (GEMM1): A = fp32 emb, split hi/lo IN-KERNEL during staging.
//                 epilogue: relu -> write split bf16 hi/lo.
// MODE 1 (GEMM2): A = pre-split hi/lo via global_load_lds.
//                 epilogue: bf16(acc + bias + resid)  (xfb, halves write traffic)
// 128x128 tile, BK=32, 256 thr (4 waves 2x2), wave tile 64x64 (4x4 frags).
// Single-buffer 2-barrier loop (R4-proven). T1 XCD swizzle. LDS XOR-swizzle
// on both write side and ds_read (G21).
// ---------------------------------------------------------------------------
template<int MODE>
__global__ __launch_bounds__(256, 2)
void gemm_mfma(const float* __restrict__ Af,
               const unsigned short* __restrict__ Ahi, const unsigned short* __restrict__ Alo,
               const unsigned short* __restrict__ Bhi, const unsigned short* __restrict__ Blo,
               const float* __restrict__ bias, const float* __restrict__ resid,
               unsigned short* __restrict__ out_hi, unsigned short* __restrict__ out_lo)
{
    __shared__ short8v As_hi[512], As_lo[512], Bs_hi[512], Bs_lo[512]; // 4 x 8KB

    // ---- XCD-aware swizzle: lin -> lid, then (bx,by) ----
    const int lin = blockIdx.y * gridDim.x + blockIdx.x;     // hw linear id
    const int cpx = (gridDim.x * gridDim.y) >> 3;            // 192
    const int lid = (lin & 7) * cpx + (lin >> 3);
    const int bx  = lid % 6;
    const int by  = lid / 6;

    const int tid  = threadIdx.x;
    const int w    = tid >> 6;
    const int lane = tid & 63;
    const int m0   = by * 128;
    const int n0   = bx * 128;
    const int wm   = (w >> 1) * 64;     // wave tile origin in block
    const int wn   = (w & 1) * 64;

    // ---- B staging (gld16, pre-swizzled global source, m173) ----
    const int rr = lane >> 2;          // row-within-1KB-chunk
    const int cc = lane & 3;           // 16B slot
    const int r0 = w * 32 + rr;        // chunk q=0 row (0..127)
    const int r1 = r0 + 16;            // chunk q=1 row
    const int sw0 = (cc ^ ((r0 >> 1) & 3)) * 16;   // swizzled byte-slot in row
    const int sw1 = (cc ^ ((r1 >> 1) & 3)) * 16;
    const size_t boff0 = (size_t)(n0 + r0) * 1536 + sw0;  // 768*2B row stride
    const size_t boff1 = (size_t)(n0 + r1) * 1536 + sw1;
    const char* pBhi = (const char*)Bhi; const char* pBlo = (const char*)Blo;
    short8v* const dBh0 = Bs_hi + w * 128;      short8v* const dBh1 = dBh0 + 64;
    short8v* const dBl0 = Bs_lo + w * 128;      short8v* const dBl1 = dBl0 + 64;

    // ---- A staging: MODE1 gld16 path ----
    const size_t aoff0 = (size_t)(m0 + r0) * 1536 + sw0;
    const size_t aoff1 = (size_t)(m0 + r1) * 1536 + sw1;
    const char* pAhi = (const char*)Ahi; const char* pAlo = (const char*)Alo;
    short8v* const dAh0 = As_hi + w * 128;      short8v* const dAh1 = dAh0 + 64;
    short8v* const dAl0 = As_lo + w * 128;      short8v* const dAl1 = dAl0 + 64;

    // ---- A staging: MODE0 fp32-split path (thread -> row, k-half) ----
    const int ar  = tid >> 1;                  // 0..127
    const int ak0 = (tid & 1) * 16;            // k-offset 0 or 16
    const int asw = (ar >> 1) & 3;
    const int sA0 = ar * 4 + (((tid & 1) * 2 + 0) ^ asw);  // slot idx for k [ak0, ak0+8)
    const int sA1 = ar * 4 + (((tid & 1) * 2 + 1) ^ asw);  // slot idx for k [ak0+8, ak0+16)
    const float* gA = (MODE == 0) ? (Af + (size_t)(m0 + ar) * D_DIM + ak0) : nullptr;

    // ---- ds_read fragment indices (loop-invariant, swizzle-matched) ----
    const int lc = lane & 15;          // row-in-frag
    const int lk = lane >> 4;          // 16B k-slot
    int ia[4], ib[4];
    #pragma unroll
    for (int m = 0; m < 4; ++m) { const int r = wm + m * 16 + lc; ia[m] = r * 4 + (lk ^ ((r >> 1) & 3)); }
    #pragma unroll
    for (int n = 0; n < 4; ++n) { const int r = wn + n * 16 + lc; ib[n] = r * 4 + (lk ^ ((r >> 1) & 3)); }

    f32x4 acc[4][4];
    #pragma unroll
    for (int m = 0; m < 4; ++m)
        #pragma unroll
        for (int n = 0; n < 4; ++n) acc[m][n] = (f32x4)(0.f);

    for (int t = 0; t < 24; ++t) {
        const int kk2 = t * 64;                // byte offset along K (bf16)
        // ---- B stage ----
        gld16(pBhi + boff0 + kk2, dBh0);
        gld16(pBhi + boff1 + kk2, dBh1);
        gld16(pBlo + boff0 + kk2, dBl0);
        gld16(pBlo + boff1 + kk2, dBl1);
        // ---- A stage ----
        if (MODE == 0) {
            const int kk = t * 32;             // element offset (fp32)
            float tmp[16];
            #pragma unroll
            for (int q = 0; q < 4; ++q) {
                const float4 f = *reinterpret_cast<const float4*>(gA + kk + q * 4);
                tmp[q * 4 + 0] = f.x; tmp[q * 4 + 1] = f.y;
                tmp[q * 4 + 2] = f.z; tmp[q * 4 + 3] = f.w;
            }
            short8v h0, h1, l0, l1;
            #pragma unroll
            for (int e = 0; e < 8; ++e) {
                unsigned short h, l;
                split2(tmp[e], h, l);     h0[e] = (short)h; l0[e] = (short)l;
                split2(tmp[8 + e], h, l); h1[e] = (short)h; l1[e] = (short)l;
            }
            As_hi[sA0] = h0; As_hi[sA1] = h1;
            As_lo[sA0] = l0; As_lo[sA1] = l1;
        } else {
            gld16(pAhi + aoff0 + kk2, dAh0);
            gld16(pAhi + aoff1 + kk2, dAh1);
            gld16(pAlo + aoff0 + kk2, dAl0);
            gld16(pAlo + aoff1 + kk2, dAl1);
        }
        __syncthreads();   // drains vmcnt+lgkm: staged tile visible to all

        short8v ah[4], al[4], bh[4], bl[4];
        #pragma unroll
        for (int m = 0; m < 4; ++m) { ah[m] = As_hi[ia[m]]; al[m] = As_lo[ia[m]]; }
        #pragma unroll
        for (int n = 0; n < 4; ++n) { bh[n] = Bs_hi[ib[n]]; bl[n] = Bs_lo[ib[n]]; }

        #pragma unroll
        for (int m = 0; m < 4; ++m)
            #pragma unroll
            for (int n = 0; n < 4; ++n) {
                acc[m][n] = __builtin_amdgcn_mfma_f32_16x16x32_bf16(ah[m], bh[n], acc[m][n], 0, 0, 0);
                acc[m][n] = __builtin_amdgcn_mfma_f32_16x16x32_bf16(ah[m], bl[n], acc[m][n], 0, 0, 0);
                acc[m][n] = __builtin_amdgcn_mfma_f32_16x16x32_bf16(al[m], bh[n], acc[m][n], 0, 0, 0);
            }
        __syncthreads();   // protect LDS before next stage
    }

    // ---- epilogue: C/D layout col=lane&15, row=(lane>>4)*4+reg (m89) ----
    const int erow = lane >> 4;
    #pragma unroll
    for (int m = 0; m < 4; ++m) {
        #pragma unroll
        for (int n = 0; n < 4; ++n) {
            const int gcol = n0 + wn + n * 16 + lc;
            const float bv = bias[gcol];
            const int grow0 = m0 + wm + m * 16 + erow * 4;
            #pragma unroll
            for (int r = 0; r < 4; ++r) {
                float v = acc[m][n][r] + bv;
                const size_t o = (size_t)(grow0 + r) * D_DIM + gcol;
                if (MODE == 0) {
                    v = fmaxf(v, 0.f);
                    unsigned short h, l; split2(v, h, l);
                    out_hi[o] = h; out_lo[o] = l;
                } else {
                    out_hi[o] = f2bf(v + resid[o]);   // xfb (bf16)
                }
            }
        }
    }
}

// ---------------------------------------------------------------------------
// LayerNorm: reads xfb[M,768] bf16, writes ff as bf16 + rnorm[m].
// One wave per row, 4 rows per block.
// ---------------------------------------------------------------------------
__global__ __launch_bounds__(256)
void ln_kernel(const unsigned short* __restrict__ xfb, const float* __restrict__ gamma,
               const float* __restrict__ beta, unsigned short* __restrict__ ffb,
               float* __restrict__ rnorm)
{
    const int wave = threadIdx.x >> 6;
    const int lane = threadIdx.x & 63;
    const int row  = blockIdx.x * 4 + wave;
    const unsigned short* xr = xfb + (size_t)row * D_DIM;
    unsigned short* fr = ffb + (size_t)row * D_DIM;

    float v[12];
    float sum = 0.f, sumsq = 0.f;
    #pragma unroll
    for (int j = 0; j < 3; ++j) {
        const ushort4 f = *reinterpret_cast<const ushort4*>(&xr[j * 256 + lane * 4]);
        v[j * 4 + 0] = bf2f(f.x); v[j * 4 + 1] = bf2f(f.y);
        v[j * 4 + 2] = bf2f(f.z); v[j * 4 + 3] = bf2f(f.w);
    }
    #pragma unroll
    for (int e = 0; e < 12; ++e) { sum += v[e]; sumsq = fmaf(v[e], v[e], sumsq); }
    #pragma unroll
    for (int m = 1; m < 64; m <<= 1) {
        sum   += __shfl_xor(sum, m);
        sumsq += __shfl_xor(sumsq, m);
    }
    const float mean = sum * (1.f / 768.f);
    const float var  = sumsq * (1.f / 768.f) - mean * mean;
    const float rstd = 1.f / sqrtf(var + LN_EPS);

    float nsq = 0.f;
    #pragma unroll
    for (int j = 0; j < 3; ++j) {
        const int c = j * 256 + lane * 4;
        const float4 g  = *reinterpret_cast<const float4*>(&gamma[c]);
        const float4 bt = *reinterpret_cast<const float4*>(&beta[c]);
        float4 o;
        o.x = fmaf(g.x * (v[j*4+0] - mean), rstd, bt.x);
        o.y = fmaf(g.y * (v[j*4+1] - mean), rstd, bt.y);
        o.z = fmaf(g.z * (v[j*4+2] - mean), rstd, bt.z);
        o.w = fmaf(g.w * (v[j*4+3] - mean), rstd, bt.w);
        nsq = fmaf(o.x, o.x, nsq); nsq = fmaf(o.y, o.y, nsq);
        nsq = fmaf(o.z, o.z, nsq); nsq = fmaf(o.w, o.w, nsq);
        ushort4 ob;
        ob.x = f2bf(o.x); ob.y = f2bf(o.y); ob.z = f2bf(o.z); ob.w = f2bf(o.w);
        *reinterpret_cast<ushort4*>(&fr[c]) = ob;
    }
    #pragma unroll
    for (int m = 1; m < 64; m <<= 1) nsq += __shfl_xor(nsq, m);
    if (lane == 0) rnorm[row] = 1.f / fmaxf(sqrtf(nsq), COS_EPS);
}

// ---------------------------------------------------------------------------
// s_part[b][q][d] = sum_{l in quarter q} ff[b][l][d] * rnorm[b][l]
// ---------------------------------------------------------------------------
__global__ __launch_bounds__(256)
void colsum_kernel(const unsigned short* __restrict__ ffb, const float* __restrict__ rnorm,
                   float* __restrict__ s_part)
{
    const int c = blockIdx.x * 256 + threadIdx.x;
    const int q = blockIdx.y;
    const int b = blockIdx.z;
    const unsigned short* fb = ffb + (size_t)b * L_DIM * D_DIM;
    const float* rb = rnorm + b * L_DIM;
    float acc = 0.f;
    #pragma unroll 4
    for (int l = q * 128; l < q * 128 + 128; ++l)
        acc = fmaf(bf2f(fb[(size_t)l * D_DIM + c]), rb[l], acc);
    s_part[((size_t)b * 4 + q) * D_DIM + c] = acc;
}

// ---------------------------------------------------------------------------
// Build Wcat_t[b][n][k] bf16: n=0..2 Wy, n=3..7 Wz, n=8 s_b (summed partials),
// n=9..15 zero. One block per b.
// ---------------------------------------------------------------------------
__global__ __launch_bounds__(256)
void wcat_kernel(const float* __restrict__ Wy, const float* __restrict__ Wz,
                 const float* __restrict__ s_part, unsigned short* __restrict__ wcat)
{
    const int b = blockIdx.x;
    unsigned short* wb = wcat + (size_t)b * NCAT * D_DIM;
    const float* sp = s_part + (size_t)b * 4 * D_DIM;
    for (int k = threadIdx.x; k < D_DIM; k += 256) {
        #pragma unroll
        for (int y = 0; y < YD; ++y) wb[y * D_DIM + k] = f2bf(Wy[k * YD + y]);
        #pragma unroll
        for (int z = 0; z < ZD; ++z) wb[(YD + z) * D_DIM + k] = f2bf(Wz[k * ZD + z]);
        wb[8 * D_DIM + k] = f2bf(sp[k] + sp[D_DIM + k] + sp[2 * D_DIM + k] + sp[3 * D_DIM + k]);
        #pragma unroll
        for (int n = 9; n < NCAT; ++n) wb[n * D_DIM + k] = 0;
    }
}

// ---------------------------------------------------------------------------
// rowout via MFMA: D[M,16] = ff[M,768] @ Wcat_t^T; cols 0-2 -> out1+by,
// cols 3-7 -> out2+bz, col 8 -> aw = 1/(1+exp(ds * rnorm / L)).
// Block = 64 rows (4 waves x 16), all in one b. 24 MFMA, no LDS.
// ---------------------------------------------------------------------------
__global__ __launch_bounds__(256)
void rowout_mfma(const unsigned short* __restrict__ ffb, const unsigned short* __restrict__ wcat,
                 const float* __restrict__ rnorm,
                 const float* __restrict__ by, const float* __restrict__ bz,
                 float* __restrict__ out1, float* __restrict__ out2,
                 float* __restrict__ aw)
{
    const int w    = threadIdx.x >> 6;
    const int lane = threadIdx.x & 63;
    const int rbase = blockIdx.x * 64 + w * 16;
    const int b     = blockIdx.x >> 3;                 // 8 blocks per b
    const int idx  = lane & 15;                        // A-row / B-col index
    const int ak   = (lane >> 4) * 8;                  // k-offset within 32

    const unsigned short* arow = ffb + (size_t)(rbase + idx) * D_DIM + ak;
    const unsigned short* brow = wcat + ((size_t)b * NCAT + idx) * D_DIM + ak;

    f32x4 acc = (f32x4)(0.f);
    #pragma unroll 4
    for (int t = 0; t < 24; ++t) {
        const short8v a  = *reinterpret_cast<const short8v*>(arow + t * 32);
        const short8v bb = *reinterpret_cast<const short8v*>(brow + t * 32);
        acc = __builtin_amdgcn_mfma_f32_16x16x32_bf16(a, bb, acc, 0, 0, 0);
    }

    const int erow = lane >> 4;
    #pragma unroll
    for (int r = 0; r < 4; ++r) {
        const int row = rbase + erow * 4 + r;
        const float v = acc[r];
        if (idx < YD) {
            out1[(size_t)row * YD + idx] = v + by[idx];
        } else if (idx < YD + ZD) {
            out2[(size_t)row * ZD + (idx - YD)] = v + bz[idx - YD];
        } else if (idx == 8) {
            const float a_ = v * rnorm[row] * (1.f / (float)L_DIM);
            aw[row] = 1.f / (1.f + expf(a_));
        }
    }
}

__global__ __launch_bounds__(512)
void softmax_kernel(const float* __restrict__ aw, float* __restrict__ attn)
{
    __shared__ float red[8];
    const int b = blockIdx.x;
    const int t = threadIdx.x;
    const int wave = t >> 6, lane = t & 63;
    const float v = aw[b * L_DIM + t];

    float mx = v;
    #pragma unroll
    for (int m = 1; m < 64; m <<= 1) mx = fmaxf(mx, __shfl_xor(mx, m));
    if (lane == 0) red[wave] = mx;
    __syncthreads();
    mx = red[0];
    #pragma unroll
    for (int w = 1; w < 8; ++w) mx = fmaxf(mx, red[w]);
    __syncthreads();

    const float e = expf(v - mx);
    float sm = e;
    #pragma unroll
    for (int m = 1; m < 64; m <<= 1) sm += __shfl_xor(sm, m);
    if (lane == 0) red[wave] = sm;
    __syncthreads();
    float tot = 0.f;
    #pragma unroll
    for (int w = 0; w < 8; ++w) tot += red[w];

    attn[b * L_DIM + t] = e / tot;
}

// ---------------------------------------------------------------------------
extern "C" void kernel_launch(void* const* d_in, const int* in_sizes, int n_in,
                              void* d_out, int out_size, void* d_ws, size_t ws_size,
                              hipStream_t stream)
{
    const float* emb   = (const float*)d_in[0];
    const float* W1    = (const float*)d_in[1];
    const float* b1    = (const float*)d_in[2];
    const float* W2    = (const float*)d_in[3];
    const float* b2    = (const float*)d_in[4];
    const float* gamma = (const float*)d_in[5];
    const float* beta  = (const float*)d_in[6];
    const float* Wy    = (const float*)d_in[7];
    const float* by    = (const float*)d_in[8];
    const float* Wz    = (const float*)d_in[9];
    const float* bz    = (const float*)d_in[10];

    float* out = (float*)d_out;
    char*  p   = (char*)d_ws;

    const size_t MD = (size_t)M_DIM * D_DIM;

    unsigned short* h1_hi = (unsigned short*)p;  p += MD * 2;
    unsigned short* h1_lo = (unsigned short*)p;  p += MD * 2;
    unsigned short* xfb   = (unsigned short*)p;  p += MD * 2;   // bf16 x
    unsigned short* w1t_hi = (unsigned short*)p; p += (size_t)D_DIM * D_DIM * 2;
    unsigned short* w1t_lo = (unsigned short*)p; p += (size_t)D_DIM * D_DIM * 2;
    unsigned short* w2t_hi = (unsigned short*)p; p += (size_t)D_DIM * D_DIM * 2;
    unsigned short* w2t_lo = (unsigned short*)p; p += (size_t)D_DIM * D_DIM * 2;
    float* rnorm  = (float*)p;                   p += (size_t)M_DIM * 4;
    float* awb    = (float*)p;                   p += (size_t)M_DIM * 4;
    float* s_part = (float*)p;                   p += (size_t)B_DIM * 4 * D_DIM * 4;
    unsigned short* wcat = (unsigned short*)p;   // B*16*768 bf16

    // ff (bf16) aliases h1_hi: h1 hi/lo are dead after GEMM2 completes.
    unsigned short* ffb = h1_hi;

    float* out1 = out;
    float* out2 = out + (size_t)M_DIM * YD;
    float* attn = out + (size_t)M_DIM * (YD + ZD);

    tsplit_kernel<<<dim3(24, 24, 2), 256, 0, stream>>>(W1, W2, w1t_hi, w1t_lo,
                                                       w2t_hi, w2t_lo);

    const dim3 gg(D_DIM / 128, M_DIM / 128);     // (6, 256) = 1536 wgs, %8==0
    gemm_mfma<0><<<gg, 256, 0, stream>>>(emb, nullptr, nullptr, w1t_hi, w1t_lo,
                                         b1, nullptr, h1_hi, h1_lo);
    gemm_mfma<1><<<gg, 256, 0, stream>>>(nullptr, h1_hi, h1_lo, w2t_hi, w2t_lo,
                                         b2, emb, xfb, nullptr);

    ln_kernel<<<M_DIM / 4, 256, 0, stream>>>(xfb, gamma, beta, ffb, rnorm);
    colsum_kernel<<<dim3(3, 4, B_DIM), 256, 0, stream>>>(ffb, rnorm, s_part);
    wcat_kernel<<<B_DIM, 256, 0, stream>>>(Wy, Wz, s_part, wcat);
    rowout_mfma<<<M_DIM / 64, 256, 0, stream>>>(ffb, wcat, rnorm, by, bz,
                                                out1, out2, awb);
    softmax_kernel<<<B_DIM, 512, 0, stream>>>(awb, attn);
}

// Round 8
// 403.818 us; speedup vs baseline: 1.2952x; 1.0555x over previous
//
#include <hip/hip_runtime.h>
#include <hip/hip_bf16.h>
#include <math.h>

#define D_DIM 768
#define B_DIM 64
#define L_DIM 512
#define M_DIM (B_DIM * L_DIM)   /* 32768 rows */
#define YD 3
#define ZD 5
#define NCAT 16                  /* Wy(3) | Wz(5) | s(1) | pad(7) */
#define LN_EPS 1e-5f
#define COS_EPS 1e-8f

typedef short short8v __attribute__((ext_vector_type(8)));
typedef _Float16 half8v __attribute__((ext_vector_type(8)));
typedef float f32x4  __attribute__((ext_vector_type(4)));

// ---------------------------------------------------------------------------
// bf16 helpers (RNE) -- used by the tail (ff / xfb / wcat)
// ---------------------------------------------------------------------------
__device__ __forceinline__ unsigned short f2bf(float f) {
    unsigned u = __builtin_bit_cast(unsigned, f);
    u = (u + 0x7fffu + ((u >> 16) & 1u)) >> 16;
    return (unsigned short)u;
}
__device__ __forceinline__ float bf2f(unsigned short h) {
    unsigned u = ((unsigned)h) << 16;
    return __builtin_bit_cast(float, u);
}
// fp16 helpers: x = hi + lo, hi=f16(x), lo=f16(x-hi); |x - hi - lo| ~ 2^-22|x|
__device__ __forceinline__ unsigned short f2h(float f) {
    _Float16 h = (_Float16)f;
    return __builtin_bit_cast(unsigned short, h);
}
__device__ __forceinline__ float h2f(unsigned short u) {
    return (float)__builtin_bit_cast(_Float16, u);
}
__device__ __forceinline__ void splith(float v, unsigned short& h, unsigned short& l) {
    h = f2h(v);
    l = f2h(v - h2f(h));
}

// async global->LDS, 16B per lane, wave-uniform LDS base + lane*16
__device__ __forceinline__ void gld16(const void* g, void* l) {
    __builtin_amdgcn_global_load_lds(
        (const __attribute__((address_space(1))) void*)g,
        (__attribute__((address_space(3))) void*)l, 16, 0, 0);
}

// ---------------------------------------------------------------------------
// W[768][768] -> Wt_h/Wt_l[n][k] (transposed, fp16 split). 32x32 LDS tiles.
// blockIdx.z selects W1 or W2.
// ---------------------------------------------------------------------------
__global__ __launch_bounds__(256)
void tsplit_kernel(const float* __restrict__ W1, const float* __restrict__ W2,
                   unsigned short* __restrict__ t1h, unsigned short* __restrict__ t1l,
                   unsigned short* __restrict__ t2h, unsigned short* __restrict__ t2l)
{
    const float* W = blockIdx.z ? W2 : W1;
    unsigned short* th = blockIdx.z ? t2h : t1h;
    unsigned short* tl = blockIdx.z ? t2l : t1l;
    __shared__ float t[32][33];
    const int tx = threadIdx.x & 31, ty = threadIdx.x >> 5;
    const int n0 = blockIdx.x * 32, k0 = blockIdx.y * 32;
    #pragma unroll
    for (int j = 0; j < 4; ++j)
        t[ty + 8 * j][tx] = W[(size_t)(k0 + ty + 8 * j) * D_DIM + n0 + tx];
    __syncthreads();
    #pragma unroll
    for (int j = 0; j < 4; ++j) {
        const float v = t[tx][ty + 8 * j];
        unsigned short h, l; splith(v, h, l);
        const size_t o = (size_t)(n0 + ty + 8 * j) * D_DIM + k0 + tx;
        th[o] = h; tl[o] = l;
    }
}

// ---------------------------------------------------------------------------
// MFMA GEMM (fp16 2-term): out = epilogue( A_h @ (B_h + B_l)^T' + bias )
//   error ~ A_lo*B ~ 2^-11 rel — an order below the tail's bf16 rounding.
// MODE 0 (GEMM1): A = fp32 emb, cvt to fp16 IN-KERNEL during staging.
//                 epilogue: relu -> fp16 h1 (single buffer, 48MB).
// MODE 1 (GEMM2): A = fp16 h1 via global_load_lds.
//                 epilogue: bf16(acc + bias + resid) -> xfb.
// 128x128 tile, BK=32, 256 thr (4 waves 2x2), wave tile 64x64 (4x4 frags).
// 32 MFMA/K-step (was 48). LDS 24KB. Single-buffer 2-barrier loop.
// T1 XCD swizzle; LDS slot XOR-swizzle on both write side and ds_read (G21).
// ---------------------------------------------------------------------------
template<int MODE>
__global__ __launch_bounds__(256, 4)
void gemm_mfma(const float* __restrict__ Af,
               const unsigned short* __restrict__ Ah,
               const unsigned short* __restrict__ Bh, const unsigned short* __restrict__ Bl,
               const float* __restrict__ bias, const float* __restrict__ resid,
               unsigned short* __restrict__ out_u16)
{
    __shared__ short8v As[512], Bs_h[512], Bs_l[512];   // 3 x 8KB

    // ---- XCD-aware swizzle: lin -> lid, then (bx,by) ----
    const int lin = blockIdx.y * gridDim.x + blockIdx.x;     // hw linear id
    const int cpx = (gridDim.x * gridDim.y) >> 3;            // 192
    const int lid = (lin & 7) * cpx + (lin >> 3);
    const int bx  = lid % 6;
    const int by  = lid / 6;

    const int tid  = threadIdx.x;
    const int w    = tid >> 6;
    const int lane = tid & 63;
    const int m0   = by * 128;
    const int n0   = bx * 128;
    const int wm   = (w >> 1) * 64;     // wave tile origin in block
    const int wn   = (w & 1) * 64;

    // ---- staging geometry (rows of 32 k-elems x 2B = 64B = 4 x 16B slots) ----
    const int rr = lane >> 2;          // row-within-1KB-chunk
    const int cc = lane & 3;           // 16B slot
    const int r0 = w * 32 + rr;        // chunk q=0 row (0..127)
    const int r1 = r0 + 16;            // chunk q=1 row
    const int sw0 = (cc ^ ((r0 >> 1) & 3)) * 16;   // swizzled byte-slot in row
    const int sw1 = (cc ^ ((r1 >> 1) & 3)) * 16;
    const size_t boff0 = (size_t)(n0 + r0) * 1536 + sw0;  // 768*2B row stride
    const size_t boff1 = (size_t)(n0 + r1) * 1536 + sw1;
    const char* pBh = (const char*)Bh; const char* pBl = (const char*)Bl;
    short8v* const dBh0 = Bs_h + w * 128;      short8v* const dBh1 = dBh0 + 64;
    short8v* const dBl0 = Bs_l + w * 128;      short8v* const dBl1 = dBl0 + 64;

    // ---- A staging: MODE1 gld16 path (fp16 single) ----
    const size_t aoff0 = (size_t)(m0 + r0) * 1536 + sw0;
    const size_t aoff1 = (size_t)(m0 + r1) * 1536 + sw1;
    const char* pAh = (const char*)Ah;
    short8v* const dA0 = As + w * 128;         short8v* const dA1 = dA0 + 64;

    // ---- A staging: MODE0 fp32->fp16 cvt path (thread -> row, k-half) ----
    const int ar  = tid >> 1;                  // 0..127
    const int ak0 = (tid & 1) * 16;            // k-offset 0 or 16
    const int asw = (ar >> 1) & 3;
    const int sA0 = ar * 4 + (((tid & 1) * 2 + 0) ^ asw);  // slot for k [ak0, ak0+8)
    const int sA1 = ar * 4 + (((tid & 1) * 2 + 1) ^ asw);  // slot for k [ak0+8, ak0+16)
    const float* gA = (MODE == 0) ? (Af + (size_t)(m0 + ar) * D_DIM + ak0) : nullptr;

    // ---- ds_read fragment indices (loop-invariant, swizzle-matched) ----
    const int lc = lane & 15;          // row-in-frag
    const int lk = lane >> 4;          // 16B k-slot
    int ia[4], ib[4];
    #pragma unroll
    for (int m = 0; m < 4; ++m) { const int r = wm + m * 16 + lc; ia[m] = r * 4 + (lk ^ ((r >> 1) & 3)); }
    #pragma unroll
    for (int n = 0; n < 4; ++n) { const int r = wn + n * 16 + lc; ib[n] = r * 4 + (lk ^ ((r >> 1) & 3)); }

    f32x4 acc[4][4];
    #pragma unroll
    for (int m = 0; m < 4; ++m)
        #pragma unroll
        for (int n = 0; n < 4; ++n) acc[m][n] = (f32x4)(0.f);

    for (int t = 0; t < 24; ++t) {
        const int kk2 = t * 64;                // byte offset along K (fp16)
        // ---- B stage ----
        gld16(pBh + boff0 + kk2, dBh0);
        gld16(pBh + boff1 + kk2, dBh1);
        gld16(pBl + boff0 + kk2, dBl0);
        gld16(pBl + boff1 + kk2, dBl1);
        // ---- A stage ----
        if (MODE == 0) {
            const int kk = t * 32;             // element offset (fp32)
            float tmp[16];
            #pragma unroll
            for (int q = 0; q < 4; ++q) {
                const float4 f = *reinterpret_cast<const float4*>(gA + kk + q * 4);
                tmp[q * 4 + 0] = f.x; tmp[q * 4 + 1] = f.y;
                tmp[q * 4 + 2] = f.z; tmp[q * 4 + 3] = f.w;
            }
            short8v h0, h1;
            #pragma unroll
            for (int e = 0; e < 8; ++e) {
                h0[e] = (short)f2h(tmp[e]);
                h1[e] = (short)f2h(tmp[8 + e]);
            }
            As[sA0] = h0; As[sA1] = h1;
        } else {
            gld16(pAh + aoff0 + kk2, dA0);
            gld16(pAh + aoff1 + kk2, dA1);
        }
        __syncthreads();   // drains vmcnt+lgkm: staged tile visible to all

        half8v a[4], bh[4], bl[4];
        #pragma unroll
        for (int m = 0; m < 4; ++m) a[m] = __builtin_bit_cast(half8v, As[ia[m]]);
        #pragma unroll
        for (int n = 0; n < 4; ++n) {
            bh[n] = __builtin_bit_cast(half8v, Bs_h[ib[n]]);
            bl[n] = __builtin_bit_cast(half8v, Bs_l[ib[n]]);
        }

        #pragma unroll
        for (int m = 0; m < 4; ++m)
            #pragma unroll
            for (int n = 0; n < 4; ++n) {
                acc[m][n] = __builtin_amdgcn_mfma_f32_16x16x32_f16(a[m], bh[n], acc[m][n], 0, 0, 0);
                acc[m][n] = __builtin_amdgcn_mfma_f32_16x16x32_f16(a[m], bl[n], acc[m][n], 0, 0, 0);
            }
        __syncthreads();   // protect LDS before next stage
    }

    // ---- epilogue: C/D layout col=lane&15, row=(lane>>4)*4+reg (m89) ----
    const int erow = lane >> 4;
    #pragma unroll
    for (int m = 0; m < 4; ++m) {
        #pragma unroll
        for (int n = 0; n < 4; ++n) {
            const int gcol = n0 + wn + n * 16 + lc;
            const float bv = bias[gcol];
            const int grow0 = m0 + wm + m * 16 + erow * 4;
            #pragma unroll
            for (int r = 0; r < 4; ++r) {
                float v = acc[m][n][r] + bv;
                const size_t o = (size_t)(grow0 + r) * D_DIM + gcol;
                if (MODE == 0) {
                    out_u16[o] = f2h(fmaxf(v, 0.f));     // h1 fp16
                } else {
                    out_u16[o] = f2bf(v + resid[o]);     // xfb bf16
                }
            }
        }
    }
}

// ---------------------------------------------------------------------------
// LayerNorm: reads xfb[M,768] bf16, writes ff as bf16 + rnorm[m].
// ---------------------------------------------------------------------------
__global__ __launch_bounds__(256)
void ln_kernel(const unsigned short* __restrict__ xfb, const float* __restrict__ gamma,
               const float* __restrict__ beta, unsigned short* __restrict__ ffb,
               float* __restrict__ rnorm)
{
    const int wave = threadIdx.x >> 6;
    const int lane = threadIdx.x & 63;
    const int row  = blockIdx.x * 4 + wave;
    const unsigned short* xr = xfb + (size_t)row * D_DIM;
    unsigned short* fr = ffb + (size_t)row * D_DIM;

    float v[12];
    float sum = 0.f, sumsq = 0.f;
    #pragma unroll
    for (int j = 0; j < 3; ++j) {
        const ushort4 f = *reinterpret_cast<const ushort4*>(&xr[j * 256 + lane * 4]);
        v[j * 4 + 0] = bf2f(f.x); v[j * 4 + 1] = bf2f(f.y);
        v[j * 4 + 2] = bf2f(f.z); v[j * 4 + 3] = bf2f(f.w);
    }
    #pragma unroll
    for (int e = 0; e < 12; ++e) { sum += v[e]; sumsq = fmaf(v[e], v[e], sumsq); }
    #pragma unroll
    for (int m = 1; m < 64; m <<= 1) {
        sum   += __shfl_xor(sum, m);
        sumsq += __shfl_xor(sumsq, m);
    }
    const float mean = sum * (1.f / 768.f);
    const float var  = sumsq * (1.f / 768.f) - mean * mean;
    const float rstd = 1.f / sqrtf(var + LN_EPS);

    float nsq = 0.f;
    #pragma unroll
    for (int j = 0; j < 3; ++j) {
        const int c = j * 256 + lane * 4;
        const float4 g  = *reinterpret_cast<const float4*>(&gamma[c]);
        const float4 bt = *reinterpret_cast<const float4*>(&beta[c]);
        float4 o;
        o.x = fmaf(g.x * (v[j*4+0] - mean), rstd, bt.x);
        o.y = fmaf(g.y * (v[j*4+1] - mean), rstd, bt.y);
        o.z = fmaf(g.z * (v[j*4+2] - mean), rstd, bt.z);
        o.w = fmaf(g.w * (v[j*4+3] - mean), rstd, bt.w);
        nsq = fmaf(o.x, o.x, nsq); nsq = fmaf(o.y, o.y, nsq);
        nsq = fmaf(o.z, o.z, nsq); nsq = fmaf(o.w, o.w, nsq);
        ushort4 ob;
        ob.x = f2bf(o.x); ob.y = f2bf(o.y); ob.z = f2bf(o.z); ob.w = f2bf(o.w);
        *reinterpret_cast<ushort4*>(&fr[c]) = ob;
    }
    #pragma unroll
    for (int m = 1; m < 64; m <<= 1) nsq += __shfl_xor(nsq, m);
    if (lane == 0) rnorm[row] = 1.f / fmaxf(sqrtf(nsq), COS_EPS);
}

// ---------------------------------------------------------------------------
// s_part[b][q][d] = sum_{l in quarter q} ff[b][l][d] * rnorm[b][l]
// ---------------------------------------------------------------------------
__global__ __launch_bounds__(256)
void colsum_kernel(const unsigned short* __restrict__ ffb, const float* __restrict__ rnorm,
                   float* __restrict__ s_part)
{
    const int c = blockIdx.x * 256 + threadIdx.x;
    const int q = blockIdx.y;
    const int b = blockIdx.z;
    const unsigned short* fb = ffb + (size_t)b * L_DIM * D_DIM;
    const float* rb = rnorm + b * L_DIM;
    float acc = 0.f;
    #pragma unroll 4
    for (int l = q * 128; l < q * 128 + 128; ++l)
        acc = fmaf(bf2f(fb[(size_t)l * D_DIM + c]), rb[l], acc);
    s_part[((size_t)b * 4 + q) * D_DIM + c] = acc;
}

// ---------------------------------------------------------------------------
// Build Wcat_t[b][n][k] bf16: n=0..2 Wy, n=3..7 Wz, n=8 s_b, n=9..15 zero.
// ---------------------------------------------------------------------------
__global__ __launch_bounds__(256)
void wcat_kernel(const float* __restrict__ Wy, const float* __restrict__ Wz,
                 const float* __restrict__ s_part, unsigned short* __restrict__ wcat)
{
    const int b = blockIdx.x;
    unsigned short* wb = wcat + (size_t)b * NCAT * D_DIM;
    const float* sp = s_part + (size_t)b * 4 * D_DIM;
    for (int k = threadIdx.x; k < D_DIM; k += 256) {
        #pragma unroll
        for (int y = 0; y < YD; ++y) wb[y * D_DIM + k] = f2bf(Wy[k * YD + y]);
        #pragma unroll
        for (int z = 0; z < ZD; ++z) wb[(YD + z) * D_DIM + k] = f2bf(Wz[k * ZD + z]);
        wb[8 * D_DIM + k] = f2bf(sp[k] + sp[D_DIM + k] + sp[2 * D_DIM + k] + sp[3 * D_DIM + k]);
        #pragma unroll
        for (int n = 9; n < NCAT; ++n) wb[n * D_DIM + k] = 0;
    }
}

// ---------------------------------------------------------------------------
// rowout via MFMA: D[M,16] = ff[M,768] @ Wcat_t^T; cols 0-2 -> out1+by,
// cols 3-7 -> out2+bz, col 8 -> aw = 1/(1+exp(ds * rnorm / L)).
// ---------------------------------------------------------------------------
__global__ __launch_bounds__(256)
void rowout_mfma(const unsigned short* __restrict__ ffb, const unsigned short* __restrict__ wcat,
                 const float* __restrict__ rnorm,
                 const float* __restrict__ by, const float* __restrict__ bz,
                 float* __restrict__ out1, float* __restrict__ out2,
                 float* __restrict__ aw)
{
    const int w    = threadIdx.x >> 6;
    const int lane = threadIdx.x & 63;
    const int rbase = blockIdx.x * 64 + w * 16;
    const int b     = blockIdx.x >> 3;                 // 8 blocks per b
    const int idx  = lane & 15;                        // A-row / B-col index
    const int ak   = (lane >> 4) * 8;                  // k-offset within 32

    const unsigned short* arow = ffb + (size_t)(rbase + idx) * D_DIM + ak;
    const unsigned short* brow = wcat + ((size_t)b * NCAT + idx) * D_DIM + ak;

    f32x4 acc = (f32x4)(0.f);
    #pragma unroll 4
    for (int t = 0; t < 24; ++t) {
        const short8v a  = *reinterpret_cast<const short8v*>(arow + t * 32);
        const short8v bb = *reinterpret_cast<const short8v*>(brow + t * 32);
        acc = __builtin_amdgcn_mfma_f32_16x16x32_bf16(a, bb, acc, 0, 0, 0);
    }

    const int erow = lane >> 4;
    #pragma unroll
    for (int r = 0; r < 4; ++r) {
        const int row = rbase + erow * 4 + r;
        const float v = acc[r];
        if (idx < YD) {
            out1[(size_t)row * YD + idx] = v + by[idx];
        } else if (idx < YD + ZD) {
            out2[(size_t)row * ZD + (idx - YD)] = v + bz[idx - YD];
        } else if (idx == 8) {
            const float a_ = v * rnorm[row] * (1.f / (float)L_DIM);
            aw[row] = 1.f / (1.f + expf(a_));
        }
    }
}

__global__ __launch_bounds__(512)
void softmax_kernel(const float* __restrict__ aw, float* __restrict__ attn)
{
    __shared__ float red[8];
    const int b = blockIdx.x;
    const int t = threadIdx.x;
    const int wave = t >> 6, lane = t & 63;
    const float v = aw[b * L_DIM + t];

    float mx = v;
    #pragma unroll
    for (int m = 1; m < 64; m <<= 1) mx = fmaxf(mx, __shfl_xor(mx, m));
    if (lane == 0) red[wave] = mx;
    __syncthreads();
    mx = red[0];
    #pragma unroll
    for (int w = 1; w < 8; ++w) mx = fmaxf(mx, red[w]);
    __syncthreads();

    const float e = expf(v - mx);
    float sm = e;
    #pragma unroll
    for (int m = 1; m < 64; m <<= 1) sm += __shfl_xor(sm, m);
    if (lane == 0) red[wave] = sm;
    __syncthreads();
    float tot = 0.f;
    #pragma unroll
    for (int w = 0; w < 8; ++w) tot += red[w];

    attn[b * L_DIM + t] = e / tot;
}

// ---------------------------------------------------------------------------
extern "C" void kernel_launch(void* const* d_in, const int* in_sizes, int n_in,
                              void* d_out, int out_size, void* d_ws, size_t ws_size,
                              hipStream_t stream)
{
    const float* emb   = (const float*)d_in[0];
    const float* W1    = (const float*)d_in[1];
    const float* b1    = (const float*)d_in[2];
    const float* W2    = (const float*)d_in[3];
    const float* b2    = (const float*)d_in[4];
    const float* gamma = (const float*)d_in[5];
    const float* beta  = (const float*)d_in[6];
    const float* Wy    = (const float*)d_in[7];
    const float* by    = (const float*)d_in[8];
    const float* Wz    = (const float*)d_in[9];
    const float* bz    = (const float*)d_in[10];

    float* out = (float*)d_out;
    char*  p   = (char*)d_ws;

    const size_t MD = (size_t)M_DIM * D_DIM;

    unsigned short* h1h   = (unsigned short*)p;  p += MD * 2;   // fp16 h1
    unsigned short* xfb   = (unsigned short*)p;  p += MD * 2;   // bf16 x
    unsigned short* w1t_h = (unsigned short*)p;  p += (size_t)D_DIM * D_DIM * 2;
    unsigned short* w1t_l = (unsigned short*)p;  p += (size_t)D_DIM * D_DIM * 2;
    unsigned short* w2t_h = (unsigned short*)p;  p += (size_t)D_DIM * D_DIM * 2;
    unsigned short* w2t_l = (unsigned short*)p;  p += (size_t)D_DIM * D_DIM * 2;
    float* rnorm  = (float*)p;                   p += (size_t)M_DIM * 4;
    float* awb    = (float*)p;                   p += (size_t)M_DIM * 4;
    float* s_part = (float*)p;                   p += (size_t)B_DIM * 4 * D_DIM * 4;
    unsigned short* wcat = (unsigned short*)p;   // B*16*768 bf16

    // ff (bf16) aliases h1h: h1 is dead after GEMM2 completes.
    unsigned short* ffb = h1h;

    float* out1 = out;
    float* out2 = out + (size_t)M_DIM * YD;
    float* attn = out + (size_t)M_DIM * (YD + ZD);

    tsplit_kernel<<<dim3(24, 24, 2), 256, 0, stream>>>(W1, W2, w1t_h, w1t_l,
                                                       w2t_h, w2t_l);

    const dim3 gg(D_DIM / 128, M_DIM / 128);     // (6, 256) = 1536 wgs, %8==0
    gemm_mfma<0><<<gg, 256, 0, stream>>>(emb, nullptr, w1t_h, w1t_l,
                                         b1, nullptr, h1h);
    gemm_mfma<1><<<gg, 256, 0, stream>>>(nullptr, h1h, w2t_h, w2t_l,
                                         b2, emb, xfb);

    ln_kernel<<<M_DIM / 4, 256, 0, stream>>>(xfb, gamma, beta, ffb, rnorm);
    colsum_kernel<<<dim3(3, 4, B_DIM), 256, 0, stream>>>(ffb, rnorm, s_part);
    wcat_kernel<<<B_DIM, 256, 0, stream>>>(Wy, Wz, s_part, wcat);
    rowout_mfma<<<M_DIM / 64, 256, 0, stream>>>(ffb, wcat, rnorm, by, bz,
                                                out1, out2, awb);
    softmax_kernel<<<B_DIM, 512, 0, stream>>>(awb, attn);
}

// Round 9
// 394.404 us; speedup vs baseline: 1.3261x; 1.0239x over previous
//
#include <hip/hip_runtime.h>
#include <hip/hip_bf16.h>
#include <math.h>

#define D_DIM 768
#define B_DIM 64
#define L_DIM 512
#define M_DIM (B_DIM * L_DIM)   /* 32768 rows */
#define YD 3
#define ZD 5
#define NCAT 16                  /* Wy(3) | Wz(5) | s(1) | pad(7) */
#define LN_EPS 1e-5f
#define COS_EPS 1e-8f

typedef short short8v __attribute__((ext_vector_type(8)));
typedef _Float16 half8v __attribute__((ext_vector_type(8)));
typedef float f32x4  __attribute__((ext_vector_type(4)));

// ---------------------------------------------------------------------------
// bf16 helpers (RNE) -- used by the tail (ff / xfb / wcat)
// ---------------------------------------------------------------------------
__device__ __forceinline__ unsigned short f2bf(float f) {
    unsigned u = __builtin_bit_cast(unsigned, f);
    u = (u + 0x7fffu + ((u >> 16) & 1u)) >> 16;
    return (unsigned short)u;
}
__device__ __forceinline__ float bf2f(unsigned short h) {
    unsigned u = ((unsigned)h) << 16;
    return __builtin_bit_cast(float, u);
}
// fp16 helpers: x = hi + lo, hi=f16(x), lo=f16(x-hi)
__device__ __forceinline__ unsigned short f2h(float f) {
    _Float16 h = (_Float16)f;
    return __builtin_bit_cast(unsigned short, h);
}
__device__ __forceinline__ float h2f(unsigned short u) {
    return (float)__builtin_bit_cast(_Float16, u);
}
__device__ __forceinline__ void splith(float v, unsigned short& h, unsigned short& l) {
    h = f2h(v);
    l = f2h(v - h2f(h));
}

// async global->LDS, 16B per lane, wave-uniform LDS base + lane*16
__device__ __forceinline__ void gld16(const void* g, void* l) {
    __builtin_amdgcn_global_load_lds(
        (const __attribute__((address_space(1))) void*)g,
        (__attribute__((address_space(3))) void*)l, 16, 0, 0);
}

// ---------------------------------------------------------------------------
// W[768][768] -> Wt_h/Wt_l[n][k] (transposed, fp16 split). 32x32 LDS tiles.
// blockIdx.z selects W1 or W2.
// ---------------------------------------------------------------------------
__global__ __launch_bounds__(256)
void tsplit_kernel(const float* __restrict__ W1, const float* __restrict__ W2,
                   unsigned short* __restrict__ t1h, unsigned short* __restrict__ t1l,
                   unsigned short* __restrict__ t2h, unsigned short* __restrict__ t2l)
{
    const float* W = blockIdx.z ? W2 : W1;
    unsigned short* th = blockIdx.z ? t2h : t1h;
    unsigned short* tl = blockIdx.z ? t2l : t1l;
    __shared__ float t[32][33];
    const int tx = threadIdx.x & 31, ty = threadIdx.x >> 5;
    const int n0 = blockIdx.x * 32, k0 = blockIdx.y * 32;
    #pragma unroll
    for (int j = 0; j < 4; ++j)
        t[ty + 8 * j][tx] = W[(size_t)(k0 + ty + 8 * j) * D_DIM + n0 + tx];
    __syncthreads();
    #pragma unroll
    for (int j = 0; j < 4; ++j) {
        const float v = t[tx][ty + 8 * j];
        unsigned short h, l; splith(v, h, l);
        const size_t o = (size_t)(n0 + ty + 8 * j) * D_DIM + k0 + tx;
        th[o] = h; tl[o] = l;
    }
}

// ---------------------------------------------------------------------------
// MFMA GEMM (fp16 2-term): out = epilogue( A_h @ (B_h + B_l)^T' + bias )
// MODE 0 (GEMM1): A = fp32 emb, cvt to fp16 IN-KERNEL during staging.
//                 epilogue: relu -> fp16 h1.
// MODE 1 (GEMM2): A = fp16 h1 via global_load_lds.
//                 epilogue: bf16(acc + bias + resid) -> xfb.
// 256x128 tile, BK=32, 512 thr (8 waves 4x2), wave tile 64x64 (4x4 frags).
// 256 MFMA per block-iter vs ONE staging stall -> stall fraction halved vs
// the 128x128 tile (R8: MfmaUtil 25%). LDS 32KB. 2-barrier loop (proven).
// T1 XCD swizzle (768 wgs %8==0). LDS slot XOR-swizzle both sides (G21).
// ---------------------------------------------------------------------------
template<int MODE>
__global__ __launch_bounds__(512, 2)
void gemm_mfma(const float* __restrict__ Af,
               const unsigned short* __restrict__ Ah,
               const unsigned short* __restrict__ Bh, const unsigned short* __restrict__ Bl,
               const float* __restrict__ bias, const float* __restrict__ resid,
               unsigned short* __restrict__ out_u16)
{
    __shared__ short8v As[1024], Bs_h[512], Bs_l[512];   // 16 + 8 + 8 KB

    // ---- XCD-aware swizzle: lin -> lid, then (bx,by) ----
    const int lin = blockIdx.y * gridDim.x + blockIdx.x;     // hw linear id
    const int cpx = (gridDim.x * gridDim.y) >> 3;            // 96
    const int lid = (lin & 7) * cpx + (lin >> 3);
    const int bx  = lid % 6;
    const int by  = lid / 6;

    const int tid  = threadIdx.x;
    const int w    = tid >> 6;          // 0..7
    const int lane = tid & 63;
    const int m0   = by * 256;
    const int n0   = bx * 128;
    const int wm   = (w >> 1) * 64;     // 0,64,128,192
    const int wn   = (w & 1) * 64;      // 0,64

    // ---- staging geometry (rows of 32 k-elems x 2B = 64B = 4 x 16B slots) ----
    const int rr = lane >> 2;          // 0..15 (row within 16-row chunk)
    const int cc = lane & 3;           // 16B slot
    // A rows (MODE 1 path): wave stages rows w*32+rr and w*32+16+rr
    const int ra0 = w * 32 + rr;
    const int ra1 = ra0 + 16;
    // B rows: wave stages row w*16+rr (one chunk each of Bh, Bl)
    const int rb  = w * 16 + rr;
    const int swa0 = (cc ^ ((ra0 >> 1) & 3)) * 16;  // pre-swizzled byte-slot
    const int swa1 = (cc ^ ((ra1 >> 1) & 3)) * 16;
    const int swb  = (cc ^ ((rb  >> 1) & 3)) * 16;
    const size_t aoff0 = (size_t)(m0 + ra0) * 1536 + swa0;  // 768*2B row stride
    const size_t aoff1 = (size_t)(m0 + ra1) * 1536 + swa1;
    const size_t boff  = (size_t)(n0 + rb ) * 1536 + swb;
    const char* pAh = (const char*)Ah;
    const char* pBh = (const char*)Bh; const char* pBl = (const char*)Bl;
    short8v* const dA0 = As + w * 128;          short8v* const dA1 = dA0 + 64;
    short8v* const dBh = Bs_h + w * 64;
    short8v* const dBl = Bs_l + w * 64;

    // ---- A staging: MODE0 fp32->fp16 cvt path (thread -> row, k-half) ----
    const int ar  = tid >> 1;                  // 0..255
    const int ak0 = (tid & 1) * 16;            // k-offset 0 or 16
    const int asw = (ar >> 1) & 3;
    const int sA0 = ar * 4 + (((tid & 1) * 2 + 0) ^ asw);
    const int sA1 = ar * 4 + (((tid & 1) * 2 + 1) ^ asw);
    const float* gA = (MODE == 0) ? (Af + (size_t)(m0 + ar) * D_DIM + ak0) : nullptr;

    // ---- ds_read fragment indices (loop-invariant, swizzle-matched) ----
    const int lc = lane & 15;          // row-in-frag
    const int lk = lane >> 4;          // 16B k-slot
    int ia[4], ib[4];
    #pragma unroll
    for (int m = 0; m < 4; ++m) { const int r = wm + m * 16 + lc; ia[m] = r * 4 + (lk ^ ((r >> 1) & 3)); }
    #pragma unroll
    for (int n = 0; n < 4; ++n) { const int r = wn + n * 16 + lc; ib[n] = r * 4 + (lk ^ ((r >> 1) & 3)); }

    f32x4 acc[4][4];
    #pragma unroll
    for (int m = 0; m < 4; ++m)
        #pragma unroll
        for (int n = 0; n < 4; ++n) acc[m][n] = (f32x4)(0.f);

    for (int t = 0; t < 24; ++t) {
        const int kk2 = t * 64;                // byte offset along K (fp16)
        // ---- B stage (2 gld16/thread) ----
        gld16(pBh + boff + kk2, dBh);
        gld16(pBl + boff + kk2, dBl);
        // ---- A stage ----
        if (MODE == 0) {
            const int kk = t * 32;             // element offset (fp32)
            float tmp[16];
            #pragma unroll
            for (int q = 0; q < 4; ++q) {
                const float4 f = *reinterpret_cast<const float4*>(gA + kk + q * 4);
                tmp[q * 4 + 0] = f.x; tmp[q * 4 + 1] = f.y;
                tmp[q * 4 + 2] = f.z; tmp[q * 4 + 3] = f.w;
            }
            short8v h0, h1;
            #pragma unroll
            for (int e = 0; e < 8; ++e) {
                h0[e] = (short)f2h(tmp[e]);
                h1[e] = (short)f2h(tmp[8 + e]);
            }
            As[sA0] = h0; As[sA1] = h1;
        } else {
            gld16(pAh + aoff0 + kk2, dA0);
            gld16(pAh + aoff1 + kk2, dA1);
        }
        __syncthreads();   // drains vmcnt+lgkm: staged tile visible to all

        half8v a[4], bh[4], bl[4];
        #pragma unroll
        for (int m = 0; m < 4; ++m) a[m] = __builtin_bit_cast(half8v, As[ia[m]]);
        #pragma unroll
        for (int n = 0; n < 4; ++n) {
            bh[n] = __builtin_bit_cast(half8v, Bs_h[ib[n]]);
            bl[n] = __builtin_bit_cast(half8v, Bs_l[ib[n]]);
        }

        #pragma unroll
        for (int m = 0; m < 4; ++m)
            #pragma unroll
            for (int n = 0; n < 4; ++n) {
                acc[m][n] = __builtin_amdgcn_mfma_f32_16x16x32_f16(a[m], bh[n], acc[m][n], 0, 0, 0);
                acc[m][n] = __builtin_amdgcn_mfma_f32_16x16x32_f16(a[m], bl[n], acc[m][n], 0, 0, 0);
            }
        __syncthreads();   // protect LDS before next stage
    }

    // ---- epilogue: C/D layout col=lane&15, row=(lane>>4)*4+reg (m89) ----
    const int erow = lane >> 4;
    #pragma unroll
    for (int m = 0; m < 4; ++m) {
        #pragma unroll
        for (int n = 0; n < 4; ++n) {
            const int gcol = n0 + wn + n * 16 + lc;
            const float bv = bias[gcol];
            const int grow0 = m0 + wm + m * 16 + erow * 4;
            #pragma unroll
            for (int r = 0; r < 4; ++r) {
                float v = acc[m][n][r] + bv;
                const size_t o = (size_t)(grow0 + r) * D_DIM + gcol;
                if (MODE == 0) {
                    out_u16[o] = f2h(fmaxf(v, 0.f));     // h1 fp16
                } else {
                    out_u16[o] = f2bf(v + resid[o]);     // xfb bf16
                }
            }
        }
    }
}

// ---------------------------------------------------------------------------
// LayerNorm: reads xfb[M,768] bf16, writes ff as bf16 + rnorm[m].
// ---------------------------------------------------------------------------
__global__ __launch_bounds__(256)
void ln_kernel(const unsigned short* __restrict__ xfb, const float* __restrict__ gamma,
               const float* __restrict__ beta, unsigned short* __restrict__ ffb,
               float* __restrict__ rnorm)
{
    const int wave = threadIdx.x >> 6;
    const int lane = threadIdx.x & 63;
    const int row  = blockIdx.x * 4 + wave;
    const unsigned short* xr = xfb + (size_t)row * D_DIM;
    unsigned short* fr = ffb + (size_t)row * D_DIM;

    float v[12];
    float sum = 0.f, sumsq = 0.f;
    #pragma unroll
    for (int j = 0; j < 3; ++j) {
        const ushort4 f = *reinterpret_cast<const ushort4*>(&xr[j * 256 + lane * 4]);
        v[j * 4 + 0] = bf2f(f.x); v[j * 4 + 1] = bf2f(f.y);
        v[j * 4 + 2] = bf2f(f.z); v[j * 4 + 3] = bf2f(f.w);
    }
    #pragma unroll
    for (int e = 0; e < 12; ++e) { sum += v[e]; sumsq = fmaf(v[e], v[e], sumsq); }
    #pragma unroll
    for (int m = 1; m < 64; m <<= 1) {
        sum   += __shfl_xor(sum, m);
        sumsq += __shfl_xor(sumsq, m);
    }
    const float mean = sum * (1.f / 768.f);
    const float var  = sumsq * (1.f / 768.f) - mean * mean;
    const float rstd = 1.f / sqrtf(var + LN_EPS);

    float nsq = 0.f;
    #pragma unroll
    for (int j = 0; j < 3; ++j) {
        const int c = j * 256 + lane * 4;
        const float4 g  = *reinterpret_cast<const float4*>(&gamma[c]);
        const float4 bt = *reinterpret_cast<const float4*>(&beta[c]);
        float4 o;
        o.x = fmaf(g.x * (v[j*4+0] - mean), rstd, bt.x);
        o.y = fmaf(g.y * (v[j*4+1] - mean), rstd, bt.y);
        o.z = fmaf(g.z * (v[j*4+2] - mean), rstd, bt.z);
        o.w = fmaf(g.w * (v[j*4+3] - mean), rstd, bt.w);
        nsq = fmaf(o.x, o.x, nsq); nsq = fmaf(o.y, o.y, nsq);
        nsq = fmaf(o.z, o.z, nsq); nsq = fmaf(o.w, o.w, nsq);
        ushort4 ob;
        ob.x = f2bf(o.x); ob.y = f2bf(o.y); ob.z = f2bf(o.z); ob.w = f2bf(o.w);
        *reinterpret_cast<ushort4*>(&fr[c]) = ob;
    }
    #pragma unroll
    for (int m = 1; m < 64; m <<= 1) nsq += __shfl_xor(nsq, m);
    if (lane == 0) rnorm[row] = 1.f / fmaxf(sqrtf(nsq), COS_EPS);
}

// ---------------------------------------------------------------------------
// s_part[b][q][d] = sum_{l in quarter q} ff[b][l][d] * rnorm[b][l]
// ---------------------------------------------------------------------------
__global__ __launch_bounds__(256)
void colsum_kernel(const unsigned short* __restrict__ ffb, const float* __restrict__ rnorm,
                   float* __restrict__ s_part)
{
    const int c = blockIdx.x * 256 + threadIdx.x;
    const int q = blockIdx.y;
    const int b = blockIdx.z;
    const unsigned short* fb = ffb + (size_t)b * L_DIM * D_DIM;
    const float* rb = rnorm + b * L_DIM;
    float acc = 0.f;
    #pragma unroll 4
    for (int l = q * 128; l < q * 128 + 128; ++l)
        acc = fmaf(bf2f(fb[(size_t)l * D_DIM + c]), rb[l], acc);
    s_part[((size_t)b * 4 + q) * D_DIM + c] = acc;
}

// ---------------------------------------------------------------------------
// Build Wcat_t[b][n][k] bf16: n=0..2 Wy, n=3..7 Wz, n=8 s_b, n=9..15 zero.
// ---------------------------------------------------------------------------
__global__ __launch_bounds__(256)
void wcat_kernel(const float* __restrict__ Wy, const float* __restrict__ Wz,
                 const float* __restrict__ s_part, unsigned short* __restrict__ wcat)
{
    const int b = blockIdx.x;
    unsigned short* wb = wcat + (size_t)b * NCAT * D_DIM;
    const float* sp = s_part + (size_t)b * 4 * D_DIM;
    for (int k = threadIdx.x; k < D_DIM; k += 256) {
        #pragma unroll
        for (int y = 0; y < YD; ++y) wb[y * D_DIM + k] = f2bf(Wy[k * YD + y]);
        #pragma unroll
        for (int z = 0; z < ZD; ++z) wb[(YD + z) * D_DIM + k] = f2bf(Wz[k * ZD + z]);
        wb[8 * D_DIM + k] = f2bf(sp[k] + sp[D_DIM + k] + sp[2 * D_DIM + k] + sp[3 * D_DIM + k]);
        #pragma unroll
        for (int n = 9; n < NCAT; ++n) wb[n * D_DIM + k] = 0;
    }
}

// ---------------------------------------------------------------------------
// rowout via MFMA: D[M,16] = ff[M,768] @ Wcat_t^T; cols 0-2 -> out1+by,
// cols 3-7 -> out2+bz, col 8 -> aw = 1/(1+exp(ds * rnorm / L)).
// ---------------------------------------------------------------------------
__global__ __launch_bounds__(256)
void rowout_mfma(const unsigned short* __restrict__ ffb, const unsigned short* __restrict__ wcat,
                 const float* __restrict__ rnorm,
                 const float* __restrict__ by, const float* __restrict__ bz,
                 float* __restrict__ out1, float* __restrict__ out2,
                 float* __restrict__ aw)
{
    const int w    = threadIdx.x >> 6;
    const int lane = threadIdx.x & 63;
    const int rbase = blockIdx.x * 64 + w * 16;
    const int b     = blockIdx.x >> 3;                 // 8 blocks per b
    const int idx  = lane & 15;                        // A-row / B-col index
    const int ak   = (lane >> 4) * 8;                  // k-offset within 32

    const unsigned short* arow = ffb + (size_t)(rbase + idx) * D_DIM + ak;
    const unsigned short* brow = wcat + ((size_t)b * NCAT + idx) * D_DIM + ak;

    f32x4 acc = (f32x4)(0.f);
    #pragma unroll 4
    for (int t = 0; t < 24; ++t) {
        const short8v a  = *reinterpret_cast<const short8v*>(arow + t * 32);
        const short8v bb = *reinterpret_cast<const short8v*>(brow + t * 32);
        acc = __builtin_amdgcn_mfma_f32_16x16x32_bf16(a, bb, acc, 0, 0, 0);
    }

    const int erow = lane >> 4;
    #pragma unroll
    for (int r = 0; r < 4; ++r) {
        const int row = rbase + erow * 4 + r;
        const float v = acc[r];
        if (idx < YD) {
            out1[(size_t)row * YD + idx] = v + by[idx];
        } else if (idx < YD + ZD) {
            out2[(size_t)row * ZD + (idx - YD)] = v + bz[idx - YD];
        } else if (idx == 8) {
            const float a_ = v * rnorm[row] * (1.f / (float)L_DIM);
            aw[row] = 1.f / (1.f + expf(a_));
        }
    }
}

__global__ __launch_bounds__(512)
void softmax_kernel(const float* __restrict__ aw, float* __restrict__ attn)
{
    __shared__ float red[8];
    const int b = blockIdx.x;
    const int t = threadIdx.x;
    const int wave = t >> 6, lane = t & 63;
    const float v = aw[b * L_DIM + t];

    float mx = v;
    #pragma unroll
    for (int m = 1; m < 64; m <<= 1) mx = fmaxf(mx, __shfl_xor(mx, m));
    if (lane == 0) red[wave] = mx;
    __syncthreads();
    mx = red[0];
    #pragma unroll
    for (int w = 1; w < 8; ++w) mx = fmaxf(mx, red[w]);
    __syncthreads();

    const float e = expf(v - mx);
    float sm = e;
    #pragma unroll
    for (int m = 1; m < 64; m <<= 1) sm += __shfl_xor(sm, m);
    if (lane == 0) red[wave] = sm;
    __syncthreads();
    float tot = 0.f;
    #pragma unroll
    for (int w = 0; w < 8; ++w) tot += red[w];

    attn[b * L_DIM + t] = e / tot;
}

// ---------------------------------------------------------------------------
extern "C" void kernel_launch(void* const* d_in, const int* in_sizes, int n_in,
                              void* d_out, int out_size, void* d_ws, size_t ws_size,
                              hipStream_t stream)
{
    const float* emb   = (const float*)d_in[0];
    const float* W1    = (const float*)d_in[1];
    const float* b1    = (const float*)d_in[2];
    const float* W2    = (const float*)d_in[3];
    const float* b2    = (const float*)d_in[4];
    const float* gamma = (const float*)d_in[5];
    const float* beta  = (const float*)d_in[6];
    const float* Wy    = (const float*)d_in[7];
    const float* by    = (const float*)d_in[8];
    const float* Wz    = (const float*)d_in[9];
    const float* bz    = (const float*)d_in[10];

    float* out = (float*)d_out;
    char*  p   = (char*)d_ws;

    const size_t MD = (size_t)M_DIM * D_DIM;

    unsigned short* h1h   = (unsigned short*)p;  p += MD * 2;   // fp16 h1
    unsigned short* xfb   = (unsigned short*)p;  p += MD * 2;   // bf16 x
    unsigned short* w1t_h = (unsigned short*)p;  p += (size_t)D_DIM * D_DIM * 2;
    unsigned short* w1t_l = (unsigned short*)p;  p += (size_t)D_DIM * D_DIM * 2;
    unsigned short* w2t_h = (unsigned short*)p;  p += (size_t)D_DIM * D_DIM * 2;
    unsigned short* w2t_l = (unsigned short*)p;  p += (size_t)D_DIM * D_DIM * 2;
    float* rnorm  = (float*)p;                   p += (size_t)M_DIM * 4;
    float* awb    = (float*)p;                   p += (size_t)M_DIM * 4;
    float* s_part = (float*)p;                   p += (size_t)B_DIM * 4 * D_DIM * 4;
    unsigned short* wcat = (unsigned short*)p;   // B*16*768 bf16

    // ff (bf16) aliases h1h: h1 is dead after GEMM2 completes.
    unsigned short* ffb = h1h;

    float* out1 = out;
    float* out2 = out + (size_t)M_DIM * YD;
    float* attn = out + (size_t)M_DIM * (YD + ZD);

    tsplit_kernel<<<dim3(24, 24, 2), 256, 0, stream>>>(W1, W2, w1t_h, w1t_l,
                                                       w2t_h, w2t_l);

    const dim3 gg(D_DIM / 128, M_DIM / 256);     // (6, 128) = 768 wgs, %8==0
    gemm_mfma<0><<<gg, 512, 0, stream>>>(emb, nullptr, w1t_h, w1t_l,
                                         b1, nullptr, h1h);
    gemm_mfma<1><<<gg, 512, 0, stream>>>(nullptr, h1h, w2t_h, w2t_l,
                                         b2, emb, xfb);

    ln_kernel<<<M_DIM / 4, 256, 0, stream>>>(xfb, gamma, beta, ffb, rnorm);
    colsum_kernel<<<dim3(3, 4, B_DIM), 256, 0, stream>>>(ffb, rnorm, s_part);
    wcat_kernel<<<B_DIM, 256, 0, stream>>>(Wy, Wz, s_part, wcat);
    rowout_mfma<<<M_DIM / 64, 256, 0, stream>>>(ffb, wcat, rnorm, by, bz,
                                                out1, out2, awb);
    softmax_kernel<<<B_DIM, 512, 0, stream>>>(awb, attn);
}

// Round 10
// 376.314 us; speedup vs baseline: 1.3899x; 1.0481x over previous
//
#include <hip/hip_runtime.h>
#include <hip/hip_bf16.h>
#include <math.h>

#define D_DIM 768
#define B_DIM 64
#define L_DIM 512
#define M_DIM (B_DIM * L_DIM)   /* 32768 rows */
#define YD 3
#define ZD 5
#define NCAT 16                  /* Wy(3) | Wz(5) | s(1) | pad(7) */
#define LN_EPS 1e-5f
#define COS_EPS 1e-8f

typedef short short8v __attribute__((ext_vector_type(8)));
typedef _Float16 half8v __attribute__((ext_vector_type(8)));
typedef float f32x4  __attribute__((ext_vector_type(4)));

// ---------------------------------------------------------------------------
// bf16 helpers (RNE) -- used by the tail (ff / xfb / wcat)
// ---------------------------------------------------------------------------
__device__ __forceinline__ unsigned short f2bf(float f) {
    unsigned u = __builtin_bit_cast(unsigned, f);
    u = (u + 0x7fffu + ((u >> 16) & 1u)) >> 16;
    return (unsigned short)u;
}
__device__ __forceinline__ float bf2f(unsigned short h) {
    unsigned u = ((unsigned)h) << 16;
    return __builtin_bit_cast(float, u);
}
// fp16 helpers
__device__ __forceinline__ unsigned short f2h(float f) {
    _Float16 h = (_Float16)f;
    return __builtin_bit_cast(unsigned short, h);
}
__device__ __forceinline__ float h2f(unsigned short u) {
    return (float)__builtin_bit_cast(_Float16, u);
}
__device__ __forceinline__ void splith(float v, unsigned short& h, unsigned short& l) {
    h = f2h(v);
    l = f2h(v - h2f(h));
}

// async global->LDS, 16B per lane, wave-uniform LDS base + lane*16
__device__ __forceinline__ void gld16(const void* g, void* l) {
    __builtin_amdgcn_global_lo\
ad_lds(
        (const __attribute__((address_space(1))) void*)g,
        (__attribute__((address_space(3))) void*)l, 16, 0, 0);
}

// ---------------------------------------------------------------------------
// W[768][768] -> Wt_h/Wt_l[n][k] (transposed, fp16 split). 32x32 LDS tiles.
// ---------------------------------------------------------------------------
__global__ __launch_bounds__(256)
void tsplit_kernel(const float* __restrict__ W1, const float* __restrict__ W2,
                   unsigned short* __restrict__ t1h, unsigned short* __restrict__ t1l,
                   unsigned short* __restrict__ t2h, unsigned short* __restrict__ t2l)
{
    const float* W = blockIdx.z ? W2 : W1;
    unsigned short* th = blockIdx.z ? t2h : t1h;
    unsigned short* tl = blockIdx.z ? t2l : t1l;
    __shared__ float t[32][33];
    const int tx = threadIdx.x & 31, ty = threadIdx.x >> 5;
    const int n0 = blockIdx.x * 32, k0 = blockIdx.y * 32;
    #pragma unroll
    for (int j = 0; j < 4; ++j)
        t[ty + 8 * j][tx] = W[(size_t)(k0 + ty + 8 * j) * D_DIM + n0 + tx];
    __syncthreads();
    #pragma unroll
    for (int j = 0; j < 4; ++j) {
        const float v = t[tx][ty + 8 * j];
        unsigned short h, l; splith(v, h, l);
        const size_t o = (size_t)(n0 + ty + 8 * j) * D_DIM + k0 + tx;
        th[o] = h; tl[o] = l;
    }
}

// ---------------------------------------------------------------------------
// MFMA GEMM (fp16 2-term, T3+T4 pipelined): 128x128 tile, BK=32, 256 thr.
// Double-buffered LDS (48KB, 3 blocks/CU); per K-step: stage tile t+1 ->
// buf^1, s_waitcnt vmcnt(N) (counted: tile t drained, t+1 stays IN FLIGHT),
// raw s_barrier, compute tile t, raw s_barrier. No vmcnt(0) drain in loop.
// MODE 0: A = fp32 emb, 2-deep reg prefetch + in-LDS split. relu->fp16 h1.
// MODE 1: A = fp16 h1 via gld16. bf16(acc+bias+resid) -> xfb.
// ---------------------------------------------------------------------------
#define VMW(N) asm volatile("s_waitcnt vmcnt(" #N ")" ::: "memory")
#define SBAR() { __builtin_amdgcn_s_barrier(); __builtin_amdgcn_sched_barrier(0); }

template<int MODE>
__global__ __launch_bounds__(256, 3)
void gemm_mfma(const float* __restrict__ Af,
               const unsigned short* __restrict__ Ah,
               const unsigned short* __restrict__ Bh, const unsigned short* __restrict__ Bl,
               const float* __restrict__ bias, const float* __restrict__ resid,
               unsigned short* __restrict__ out_u16)
{
    __shared__ short8v As[2][512], Bs_h[2][512], Bs_l[2][512];   // 48 KB

    // ---- XCD-aware swizzle ----
    const int lin = blockIdx.y * gridDim.x + blockIdx.x;
    const int cpx = (gridDim.x * gridDim.y) >> 3;            // 192
    const int lid = (lin & 7) * cpx + (lin >> 3);
    const int bx  = lid % 6;
    const int by  = lid / 6;

    const int tid  = threadIdx.x;
    const int w    = tid >> 6;
    const int lane = tid & 63;
    const int m0   = by * 128;
    const int n0   = bx * 128;
    const int wm   = (w >> 1) * 64;
    const int wn   = (w & 1) * 64;

    // ---- staging geometry (pre-swizzled global source, m173/G21) ----
    const int rr = lane >> 2;
    const int cc = lane & 3;
    const int r0 = w * 32 + rr;
    const int r1 = r0 + 16;
    const int sw0 = (cc ^ ((r0 >> 1) & 3)) * 16;
    const int sw1 = (cc ^ ((r1 >> 1) & 3)) * 16;
    const size_t aoff0 = (size_t)(m0 + r0) * 1536 + sw0;
    const size_t aoff1 = (size_t)(m0 + r1) * 1536 + sw1;
    const size_t boff0 = (size_t)(n0 + r0) * 1536 + sw0;
    const size_t boff1 = (size_t)(n0 + r1) * 1536 + sw1;
    const char* pAh = (const char*)Ah;
    const char* pBh = (const char*)Bh; const char* pBl = (const char*)Bl;

    // ---- MODE0 fp32-split path (thread -> row, k-half) ----
    const int ar  = tid >> 1;
    const int ak0 = (tid & 1) * 16;
    const int asw = (ar >> 1) & 3;
    const int sA0 = ar * 4 + (((tid & 1) * 2 + 0) ^ asw);
    const int sA1 = ar * 4 + (((tid & 1) * 2 + 1) ^ asw);
    const float* gA = (MODE == 0) ? (Af + (size_t)(m0 + ar) * D_DIM + ak0) : nullptr;

    // ---- ds_read fragment indices ----
    const int lc = lane & 15;
    const int lk = lane >> 4;
    int ia[4], ib[4];
    #pragma unroll
    for (int m = 0; m < 4; ++m) { const int r = wm + m * 16 + lc; ia[m] = r * 4 + (lk ^ ((r >> 1) & 3)); }
    #pragma unroll
    for (int n = 0; n < 4; ++n) { const int r = wn + n * 16 + lc; ib[n] = r * 4 + (lk ^ ((r >> 1) & 3)); }

    f32x4 acc[4][4];
    #pragma unroll
    for (int m = 0; m < 4; ++m)
        #pragma unroll
        for (int n = 0; n < 4; ++n) acc[m][n] = (f32x4)(0.f);

    // ---- staging helpers (macros keep buffer parity static) ----
#define ASTAGE(T, B_) \
    gld16(pAh + aoff0 + (T) * 64, &As[B_][w * 128]); \
    gld16(pAh + aoff1 + (T) * 64, &As[B_][w * 128 + 64]);
#define BSTAGE(T, B_) \
    gld16(pBh + boff0 + (T) * 64, &Bs_h[B_][w * 128]); \
    gld16(pBh + boff1 + (T) * 64, &Bs_h[B_][w * 128 + 64]); \
    gld16(pBl + boff0 + (T) * 64, &Bs_l[B_][w * 128]); \
    gld16(pBl + boff1 + (T) * 64, &Bs_l[B_][w * 128 + 64]);
#define LOADF(R_, T) { \
    _Pragma("unroll") \
    for (int q = 0; q < 4; ++q) { \
        const float4 f_ = *reinterpret_cast<const float4*>(gA + (T) * 32 + q * 4); \
        R_[q * 4 + 0] = f_.x; R_[q * 4 + 1] = f_.y; \
        R_[q * 4 + 2] = f_.z; R_[q * 4 + 3] = f_.w; } }
#define SPLITW(R_, B_) { \
    short8v h0_, h1_; \
    _Pragma("unroll") \
    for (int e = 0; e < 8; ++e) { \
        h0_[e] = (short)f2h(R_[e]); \
        h1_[e] = (short)f2h(R_[8 + e]); } \
    As[B_][sA0] = h0_; As[B_][sA1] = h1_; }
#define COMPUTE(B_) { \
    half8v a_[4], bh_[4], bl_[4]; \
    _Pragma("unroll") \
    for (int m = 0; m < 4; ++m) a_[m] = __builtin_bit_cast(half8v, As[B_][ia[m]]); \
    _Pragma("unroll") \
    for (int n = 0; n < 4; ++n) { \
        bh_[n] = __builtin_bit_cast(half8v, Bs_h[B_][ib[n]]); \
        bl_[n] = __builtin_bit_cast(half8v, Bs_l[B_][ib[n]]); } \
    _Pragma("unroll") \
    for (int m = 0; m < 4; ++m) \
        _Pragma("unroll") \
        for (int n = 0; n < 4; ++n) { \
            acc[m][n] = __builtin_amdgcn_mfma_f32_16x16x32_f16(a_[m], bh_[n], acc[m][n], 0, 0, 0); \
            acc[m][n] = __builtin_amdgcn_mfma_f32_16x16x32_f16(a_[m], bl_[n], acc[m][n], 0, 0, 0); } }

    if (MODE == 0) {
        float ta[16], tb[16];
        // prologue: tile0 -> buf0 (direct), tile1 fp32 -> regs
        LOADF(ta, 0);
        LOADF(tb, 1);
        BSTAGE(0, 0);
        SPLITW(ta, 0);                       // implicit wait on ta loads
        asm volatile("s_waitcnt lgkmcnt(0)" ::: "memory");
        VMW(0);
        SBAR();
        // body: even t splits tb (odd tile), reloads ta; odd t vice versa
#define BODY0(T, CUR, NB, RHELD, RLOAD) { \
        if ((T) + 2 < 24) LOADF(RLOAD, (T) + 2); \
        if ((T) < 23) { \
            SPLITW(RHELD, NB); \
            BSTAGE((T) + 1, NB); \
            asm volatile("s_waitcnt lgkmcnt(0)" ::: "memory"); \
        } \
        if ((T) < 22) { VMW(8); } else if ((T) == 22) { VMW(4); } else { VMW(0); } \
        SBAR(); \
        COMPUTE(CUR); \
        SBAR(); }
        for (int t2 = 0; t2 < 24; t2 += 2) {
            BODY0(t2,     0, 1, tb, ta);
            BODY0(t2 + 1, 1, 0, ta, tb);
        }
#undef BODY0
    } else {
        // prologue
        ASTAGE(0, 0);
        BSTAGE(0, 0);
        VMW(0);
        SBAR();
#define BODY1(T, CUR, NB) { \
        if ((T) < 23) { \
            ASTAGE((T) + 1, NB); \
            BSTAGE((T) + 1, NB); \
            VMW(6); \
        } else { VMW(0); } \
        SBAR(); \
        COMPUTE(CUR); \
        SBAR(); }
        for (int t2 = 0; t2 < 24; t2 += 2) {
            BODY1(t2,     0, 1);
            BODY1(t2 + 1, 1, 0);
        }
#undef BODY1
    }

    // ---- epilogue: C/D layout col=lane&15, row=(lane>>4)*4+reg (m89) ----
    const int erow = lane >> 4;
    #pragma unroll
    for (int m = 0; m < 4; ++m) {
        #pragma unroll
        for (int n = 0; n < 4; ++n) {
            const int gcol = n0 + wn + n * 16 + lc;
            const float bv = bias[gcol];
            const int grow0 = m0 + wm + m * 16 + erow * 4;
            #pragma unroll
            for (int r = 0; r < 4; ++r) {
                float v = acc[m][n][r] + bv;
                const size_t o = (size_t)(grow0 + r) * D_DIM + gcol;
                if (MODE == 0) {
                    out_u16[o] = f2h(fmaxf(v, 0.f));     // h1 fp16
                } else {
                    out_u16[o] = f2bf(v + resid[o]);     // xfb bf16
                }
            }
        }
    }
#undef ASTAGE
#undef BSTAGE
#undef LOADF
#undef SPLITW
#undef COMPUTE
}

// ---------------------------------------------------------------------------
// LayerNorm: reads xfb[M,768] bf16, writes ff as bf16 + rnorm[m].
// ---------------------------------------------------------------------------
__global__ __launch_bounds__(256)
void ln_kernel(const unsigned short* __restrict__ xfb, const float* __restrict__ gamma,
               const float* __restrict__ beta, unsigned short* __restrict__ ffb,
               float* __restrict__ rnorm)
{
    const int wave = threadIdx.x >> 6;
    const int lane = threadIdx.x & 63;
    const int row  = blockIdx.x * 4 + wave;
    const unsigned short* xr = xfb + (size_t)row * D_DIM;
    unsigned short* fr = ffb + (size_t)row * D_DIM;

    float v[12];
    float sum = 0.f, sumsq = 0.f;
    #pragma unroll
    for (int j = 0; j < 3; ++j) {
        const ushort4 f = *reinterpret_cast<const ushort4*>(&xr[j * 256 + lane * 4]);
        v[j * 4 + 0] = bf2f(f.x); v[j * 4 + 1] = bf2f(f.y);
        v[j * 4 + 2] = bf2f(f.z); v[j * 4 + 3] = bf2f(f.w);
    }
    #pragma unroll
    for (int e = 0; e < 12; ++e) { sum += v[e]; sumsq = fmaf(v[e], v[e], sumsq); }
    #pragma unroll
    for (int m = 1; m < 64; m <<= 1) {
        sum   += __shfl_xor(sum, m);
        sumsq += __shfl_xor(sumsq, m);
    }
    const float mean = sum * (1.f / 768.f);
    const float var  = sumsq * (1.f / 768.f) - mean * mean;
    const float rstd = 1.f / sqrtf(var + LN_EPS);

    float nsq = 0.f;
    #pragma unroll
    for (int j = 0; j < 3; ++j) {
        const int c = j * 256 + lane * 4;
        const float4 g  = *reinterpret_cast<const float4*>(&gamma[c]);
        const float4 bt = *reinterpret_cast<const float4*>(&beta[c]);
        float4 o;
        o.x = fmaf(g.x * (v[j*4+0] - mean), rstd, bt.x);
        o.y = fmaf(g.y * (v[j*4+1] - mean), rstd, bt.y);
        o.z = fmaf(g.z * (v[j*4+2] - mean), rstd, bt.z);
        o.w = fmaf(g.w * (v[j*4+3] - mean), rstd, bt.w);
        nsq = fmaf(o.x, o.x, nsq); nsq = fmaf(o.y, o.y, nsq);
        nsq = fmaf(o.z, o.z, nsq); nsq = fmaf(o.w, o.w, nsq);
        ushort4 ob;
        ob.x = f2bf(o.x); ob.y = f2bf(o.y); ob.z = f2bf(o.z); ob.w = f2bf(o.w);
        *reinterpret_cast<ushort4*>(&fr[c]) = ob;
    }
    #pragma unroll
    for (int m = 1; m < 64; m <<= 1) nsq += __shfl_xor(nsq, m);
    if (lane == 0) rnorm[row] = 1.f / fmaxf(sqrtf(nsq), COS_EPS);
}

// ---------------------------------------------------------------------------
// s_part[b][q][d] = sum_{l in quarter q} ff[b][l][d] * rnorm[b][l]
// ---------------------------------------------------------------------------
__global__ __launch_bounds__(256)
void colsum_kernel(const unsigned short* __restrict__ ffb, const float* __restrict__ rnorm,
                   float* __restrict__ s_part)
{
    const int c = blockIdx.x * 256 + threadIdx.x;
    const int q = blockIdx.y;
    const int b = blockIdx.z;
    const unsigned short* fb = ffb + (size_t)b * L_DIM * D_DIM;
    const float* rb = rnorm + b * L_DIM;
    float acc = 0.f;
    #pragma unroll 4
    for (int l = q * 128; l < q * 128 + 128; ++l)
        acc = fmaf(bf2f(fb[(size_t)l * D_DIM + c]), rb[l], acc);
    s_part[((size_t)b * 4 + q) * D_DIM + c] = acc;
}

// ---------------------------------------------------------------------------
// Build Wcat_t[b][n][k] bf16: n=0..2 Wy, n=3..7 Wz, n=8 s_b, n=9..15 zero.
// ---------------------------------------------------------------------------
__global__ __launch_bounds__(256)
void wcat_kernel(const float* __restrict__ Wy, const float* __restrict__ Wz,
                 const float* __restrict__ s_part, unsigned short* __restrict__ wcat)
{
    const int b = blockIdx.x;
    unsigned short* wb = wcat + (size_t)b * NCAT * D_DIM;
    const float* sp = s_part + (size_t)b * 4 * D_DIM;
    for (int k = threadIdx.x; k < D_DIM; k += 256) {
        #pragma unroll
        for (int y = 0; y < YD; ++y) wb[y * D_DIM + k] = f2bf(Wy[k * YD + y]);
        #pragma unroll
        for (int z = 0; z < ZD; ++z) wb[(YD + z) * D_DIM + k] = f2bf(Wz[k * ZD + z]);
        wb[8 * D_DIM + k] = f2bf(sp[k] + sp[D_DIM + k] + sp[2 * D_DIM + k] + sp[3 * D_DIM + k]);
        #pragma unroll
        for (int n = 9; n < NCAT; ++n) wb[n * D_DIM + k] = 0;
    }
}

// ---------------------------------------------------------------------------
// rowout via MFMA: D[M,16] = ff[M,768] @ Wcat_t^T
// ---------------------------------------------------------------------------
__global__ __launch_bounds__(256)
void rowout_mfma(const unsigned short* __restrict__ ffb, const unsigned short* __restrict__ wcat,
                 const float* __restrict__ rnorm,
                 const float* __restrict__ by, const float* __restrict__ bz,
                 float* __restrict__ out1, float* __restrict__ out2,
                 float* __restrict__ aw)
{
    const int w    = threadIdx.x >> 6;
    const int lane = threadIdx.x & 63;
    const int rbase = blockIdx.x * 64 + w * 16;
    const int b     = blockIdx.x >> 3;
    const int idx  = lane & 15;
    const int ak   = (lane >> 4) * 8;

    const unsigned short* arow = ffb + (size_t)(rbase + idx) * D_DIM + ak;
    const unsigned short* brow = wcat + ((size_t)b * NCAT + idx) * D_DIM + ak;

    f32x4 acc = (f32x4)(0.f);
    #pragma unroll 4
    for (int t = 0; t < 24; ++t) {
        const short8v a  = *reinterpret_cast<const short8v*>(arow + t * 32);
        const short8v bb = *reinterpret_cast<const short8v*>(brow + t * 32);
        acc = __builtin_amdgcn_mfma_f32_16x16x32_bf16(a, bb, acc, 0, 0, 0);
    }

    const int erow = lane >> 4;
    #pragma unroll
    for (int r = 0; r < 4; ++r) {
        const int row = rbase + erow * 4 + r;
        const float v = acc[r];
        if (idx < YD) {
            out1[(size_t)row * YD + idx] = v + by[idx];
        } else if (idx < YD + ZD) {
            out2[(size_t)row * ZD + (idx - YD)] = v + bz[idx - YD];
        } else if (idx == 8) {
            const float a_ = v * rnorm[row] * (1.f / (float)L_DIM);
            aw[row] = 1.f / (1.f + expf(a_));
        }
    }
}

__global__ __launch_bounds__(512)
void softmax_kernel(const float* __restrict__ aw, float* __restrict__ attn)
{
    __shared__ float red[8];
    const int b = blockIdx.x;
    const int t = threadIdx.x;
    const int wave = t >> 6, lane = t & 63;
    const float v = aw[b * L_DIM + t];

    float mx = v;
    #pragma unroll
    for (int m = 1; m < 64; m <<= 1) mx = fmaxf(mx, __shfl_xor(mx, m));
    if (lane == 0) red[wave] = mx;
    __syncthreads();
    mx = red[0];
    #pragma unroll
    for (int w = 1; w < 8; ++w) mx = fmaxf(mx, red[w]);
    __syncthreads();

    const float e = expf(v - mx);
    float sm = e;
    #pragma unroll
    for (int m = 1; m < 64; m <<= 1) sm += __shfl_xor(sm, m);
    if (lane == 0) red[wave] = sm;
    __syncthreads();
    float tot = 0.f;
    #pragma unroll
    for (int w = 0; w < 8; ++w) tot += red[w];

    attn[b * L_DIM + t] = e / tot;
}

// ---------------------------------------------------------------------------
extern "C" void kernel_launch(void* const* d_in, const int* in_sizes, int n_in,
                              void* d_out, int out_size, void* d_ws, size_t ws_size,
                              hipStream_t stream)
{
    const float* emb   = (const float*)d_in[0];
    const float* W1    = (const float*)d_in[1];
    const float* b1    = (const float*)d_in[2];
    const float* W2    = (const float*)d_in[3];
    const float* b2    = (const float*)d_in[4];
    const float* gamma = (const float*)d_in[5];
    const float* beta  = (const float*)d_in[6];
    const float* Wy    = (const float*)d_in[7];
    const float* by    = (const float*)d_in[8];
    const float* Wz    = (const float*)d_in[9];
    const float* bz    = (const float*)d_in[10];

    float* out = (float*)d_out;
    char*  p   = (char*)d_ws;

    const size_t MD = (size_t)M_DIM * D_DIM;

    unsigned short* h1h   = (unsigned short*)p;  p += MD * 2;   // fp16 h1
    unsigned short* xfb   = (unsigned short*)p;  p += MD * 2;   // bf16 x
    unsigned short* w1t_h = (unsigned short*)p;  p += (size_t)D_DIM * D_DIM * 2;
    unsigned short* w1t_l = (unsigned short*)p;  p += (size_t)D_DIM * D_DIM * 2;
    unsigned short* w2t_h = (unsigned short*)p;  p += (size_t)D_DIM * D_DIM * 2;
    unsigned short* w2t_l = (unsigned short*)p;  p += (size_t)D_DIM * D_DIM * 2;
    float* rnorm  = (float*)p;                   p += (size_t)M_DIM * 4;
    float* awb    = (float*)p;                   p += (size_t)M_DIM * 4;
    float* s_part = (float*)p;                   p += (size_t)B_DIM * 4 * D_DIM * 4;
    unsigned short* wcat = (unsigned short*)p;   // B*16*768 bf16

    unsigned short* ffb = h1h;   // ff aliases h1 (dead after GEMM2)

    float* out1 = out;
    float* out2 = out + (size_t)M_DIM * YD;
    float* attn = out + (size_t)M_DIM * (YD + ZD);

    tsplit_kernel<<<dim3(24, 24, 2), 256, 0, stream>>>(W1, W2, w1t_h, w1t_l,
                                                       w2t_h, w2t_l);

    const dim3 gg(D_DIM / 128, M_DIM / 128);     // (6, 256) = 1536 wgs, %8==0
    gemm_mfma<0><<<gg, 256, 0, stream>>>(emb, nullptr, w1t_h, w1t_l,
                                         b1, nullptr, h1h);
    gemm_mfma<1><<<gg, 256, 0, stream>>>(nullptr, h1h, w2t_h, w2t_l,
                                         b2, emb, xfb);

    ln_kernel<<<M_DIM / 4, 256, 0, stream>>>(xfb, gamma, beta, ffb, rnorm);
    colsum_kernel<<<dim3(3, 4, B_DIM), 256, 0, stream>>>(ffb, rnorm, s_part);
    wcat_kernel<<<B_DIM, 256, 0, stream>>>(Wy, Wz, s_part, wcat);
    rowout_mfma<<<M_DIM / 64, 256, 0, stream>>>(ffb, wcat, rnorm, by, bz,
                                                out1, out2, awb);
    softmax_kernel<<<B_DIM, 512, 0, stream>>>(awb, attn);
}